// Round 1
// baseline (8654.703 us; speedup 1.0000x reference)
//
#include <hip/hip_runtime.h>
#include <math.h>

#define DEV __device__ __forceinline__

namespace {

constexpr int C = 512;
constexpr int ROWS = 32768;   // B * L

// windowed row r -> flat row in (b, y, x) order, for roll by `shift`.
// Same map serves gather (LN1 + window partition) and scatter (window reverse).
DEV int rowmap(int r, int shift) {
  int b  = r >> 10;
  int w  = (r >> 6) & 15;
  int wy = w >> 2, wx = w & 3;
  int ii = r & 63;
  int iy = ii >> 3, ix = ii & 7;
  int y = (wy * 8 + iy + shift) & 31;
  int x = (wx * 8 + ix + shift) & 31;
  return (b << 10) + (y << 5) + x;
}

DEV int region(int y) { return (y < 24) ? 0 : ((y < 28) ? 1 : 2); }

// ---------------- LayerNorm (one wave per row) ----------------
__global__ __launch_bounds__(256) void ln_kernel(
    const float* __restrict__ src, float* __restrict__ dst,
    const float* __restrict__ g, const float* __restrict__ b,
    int shift, int windowed) {
  int wid  = (blockIdx.x * 256 + threadIdx.x) >> 6;
  int lane = threadIdx.x & 63;
  if (wid >= ROWS) return;
  int srcRow = windowed ? rowmap(wid, shift) : wid;
  const float* s = src + (size_t)srcRow * C + lane * 8;
  float v[8];
  *(float4*)(v)     = *(const float4*)(s);
  *(float4*)(v + 4) = *(const float4*)(s + 4);
  float sum = 0.f;
#pragma unroll
  for (int j = 0; j < 8; j++) sum += v[j];
#pragma unroll
  for (int o = 32; o >= 1; o >>= 1) sum += __shfl_xor(sum, o);
  float mu = sum * (1.0f / 512.0f);
  float vs = 0.f;
#pragma unroll
  for (int j = 0; j < 8; j++) { float d = v[j] - mu; vs += d * d; }
#pragma unroll
  for (int o = 32; o >= 1; o >>= 1) vs += __shfl_xor(vs, o);
  float rs = rsqrtf(vs * (1.0f / 512.0f) + 1e-5f);
  float gg[8], bb[8];
  *(float4*)gg       = *(const float4*)&g[lane * 8];
  *(float4*)(gg + 4) = *(const float4*)&g[lane * 8 + 4];
  *(float4*)bb       = *(const float4*)&b[lane * 8];
  *(float4*)(bb + 4) = *(const float4*)&b[lane * 8 + 4];
  float o8[8];
#pragma unroll
  for (int j = 0; j < 8; j++) o8[j] = (v[j] - mu) * rs * gg[j] + bb[j];
  float* d0 = dst + (size_t)wid * C + lane * 8;
  *(float4*)(d0)     = *(float4*)o8;
  *(float4*)(d0 + 4) = *(float4*)(o8 + 4);
}

// ---------------- row sum of squares (one wave per row, 512 cols) ----------
__global__ __launch_bounds__(256) void rowss_kernel(
    const float* __restrict__ src, float* __restrict__ dst, int nrows) {
  int wid  = (blockIdx.x * 256 + threadIdx.x) >> 6;
  int lane = threadIdx.x & 63;
  if (wid >= nrows) return;
  const float* s = src + (size_t)wid * C + lane * 8;
  float4 a  = *(const float4*)s;
  float4 b4 = *(const float4*)(s + 4);
  float sum = a.x*a.x + a.y*a.y + a.z*a.z + a.w*a.w
            + b4.x*b4.x + b4.y*b4.y + b4.z*b4.z + b4.w*b4.w;
#pragma unroll
  for (int o = 32; o >= 1; o >>= 1) sum += __shfl_xor(sum, o);
  if (lane == 0) dst[wid] = sum;
}

// ---------------- fp32 GEMM core: 128x64 tile, BK=16, 8x4 per thread -------
template <bool BT>
DEV void gemm_core(const float* __restrict__ A, int lda,
                   const float* __restrict__ W, int ldb, int K,
                   int m0, int n0,
                   float (&As)[16][128], float (&Bs)[16][64],
                   float acc[8][4]) {
  const int t  = threadIdx.x;
  const int tx = t & 15, ty = t >> 4;
#pragma unroll
  for (int i = 0; i < 8; i++)
#pragma unroll
    for (int j = 0; j < 4; j++) acc[i][j] = 0.f;

  for (int k0 = 0; k0 < K; k0 += 16) {
    // A tile: 128x16 -> As[k][m]
#pragma unroll
    for (int rr = 0; rr < 2; rr++) {
      int idx = t + rr * 256;
      int m = idx >> 2, kq = idx & 3;
      float4 a4 = *(const float4*)&A[(size_t)(m0 + m) * lda + k0 + kq * 4];
      As[kq * 4 + 0][m] = a4.x;
      As[kq * 4 + 1][m] = a4.y;
      As[kq * 4 + 2][m] = a4.z;
      As[kq * 4 + 3][m] = a4.w;
    }
    // B tile: 16x64 -> Bs[k][n]
    if (!BT) {
      int k = t >> 4, nq = t & 15;
      float4 b4 = *(const float4*)&W[(size_t)(k0 + k) * ldb + n0 + nq * 4];
      *(float4*)&Bs[k][nq * 4] = b4;
    } else {  // W is (N x K) row-major (e.g. codebook)
      int n = t >> 2, kq = t & 3;
      float4 b4 = *(const float4*)&W[(size_t)(n0 + n) * ldb + k0 + kq * 4];
      Bs[kq * 4 + 0][n] = b4.x;
      Bs[kq * 4 + 1][n] = b4.y;
      Bs[kq * 4 + 2][n] = b4.z;
      Bs[kq * 4 + 3][n] = b4.w;
    }
    __syncthreads();
#pragma unroll
    for (int k = 0; k < 16; k++) {
      float a[8], bv[4];
      *(float4*)(a)     = *(float4*)&As[k][ty * 8];
      *(float4*)(a + 4) = *(float4*)&As[k][ty * 8 + 4];
      *(float4*)(bv)    = *(float4*)&Bs[k][tx * 4];
#pragma unroll
      for (int i = 0; i < 8; i++)
#pragma unroll
        for (int j = 0; j < 4; j++) acc[i][j] = fmaf(a[i], bv[j], acc[i][j]);
    }
    __syncthreads();
  }
}

// ---------------- GEMM + bias (+ optional exact GELU) ----------------------
template <int ACT>
__global__ __launch_bounds__(256) void gemm_bias_kernel(
    const float* __restrict__ A, int lda,
    const float* __restrict__ W, int ldb,
    const float* __restrict__ bias,
    float* __restrict__ out, int ldo, int K) {
  __shared__ float As[16][128];
  __shared__ float Bs[16][64];
  float acc[8][4];
  int m0 = blockIdx.x * 128, n0 = blockIdx.y * 64;
  gemm_core<false>(A, lda, W, ldb, K, m0, n0, As, Bs, acc);
  int tx = threadIdx.x & 15, ty = threadIdx.x >> 4;
#pragma unroll
  for (int i = 0; i < 8; i++) {
    int row = m0 + ty * 8 + i;
    float* op = out + (size_t)row * ldo + n0 + tx * 4;
#pragma unroll
    for (int j = 0; j < 4; j++) {
      float v = acc[i][j] + bias[n0 + tx * 4 + j];
      if (ACT == 1) v = 0.5f * v * (1.0f + erff(v * 0.70710678118654752f));
      op[j] = v;
    }
  }
}

// ---------------- GEMM + bias + residual (optional row permutation) --------
template <bool PERM>
__global__ __launch_bounds__(256) void gemm_resid_kernel(
    const float* __restrict__ A, int lda,
    const float* __restrict__ W, int ldb,
    const float* __restrict__ bias,
    float* __restrict__ out, int ldo, int K,
    const float* __restrict__ resid, int shift, int rowOff) {
  __shared__ float As[16][128];
  __shared__ float Bs[16][64];
  float acc[8][4];
  int m0 = blockIdx.x * 128, n0 = blockIdx.y * 64;
  gemm_core<false>(A, lda, W, ldb, K, m0, n0, As, Bs, acc);
  int tx = threadIdx.x & 15, ty = threadIdx.x >> 4;
#pragma unroll
  for (int i = 0; i < 8; i++) {
    int row  = m0 + ty * 8 + i;
    int orow = PERM ? rowmap(row, shift) : (rowOff + row);
    const float* rp = resid + (size_t)orow * ldo + n0 + tx * 4;
    float*       op = out   + (size_t)orow * ldo + n0 + tx * 4;
#pragma unroll
    for (int j = 0; j < 4; j++)
      op[j] = rp[j] + acc[i][j] + bias[n0 + tx * 4 + j];
  }
}

// ---------------- distance GEMM + per-tile argmin partial -------------------
__global__ __launch_bounds__(256) void gemm_dist_kernel(
    const float* __restrict__ A, int lda,
    const float* __restrict__ W, int ldb,
    const float* __restrict__ x2, const float* __restrict__ c2,
    float* __restrict__ pv, int* __restrict__ pi, int K) {
  __shared__ float As[16][128];
  __shared__ float Bs[16][64];
  __shared__ float redv[16][128];
  __shared__ int   redi[16][128];
  float acc[8][4];
  int m0 = blockIdx.x * 128, n0 = blockIdx.y * 64;
  gemm_core<true>(A, lda, W, ldb, K, m0, n0, As, Bs, acc);
  int tx = threadIdx.x & 15, ty = threadIdx.x >> 4;
#pragma unroll
  for (int i = 0; i < 8; i++) {
    int r = ty * 8 + i;
    float xx = x2[m0 + r];
    float best = 3.4e38f;
    int   bi   = 0;
#pragma unroll
    for (int j = 0; j < 4; j++) {
      int col = n0 + tx * 4 + j;
      float d = xx - 2.0f * acc[i][j] + c2[col];
      if (d < best) { best = d; bi = col; }   // ascending cols: first-min kept
    }
    redv[tx][r] = best;
    redi[tx][r] = bi;
  }
  __syncthreads();
  if (threadIdx.x < 128) {
    int r = threadIdx.x;
    float best = redv[0][r];
    int   bi   = redi[0][r];
#pragma unroll
    for (int xx2 = 1; xx2 < 16; xx2++) {
      float vv = redv[xx2][r];
      int   ii = redi[xx2][r];
      if (vv < best || (vv == best && ii < bi)) { best = vv; bi = ii; }
    }
    pv[(size_t)(m0 + r) * 64 + blockIdx.y] = best;
    pi[(size_t)(m0 + r) * 64 + blockIdx.y] = bi;
  }
}

// ---------------- final argmin + gather ------------------------------------
__global__ __launch_bounds__(128) void vq_out_kernel(
    const float* __restrict__ pv, const int* __restrict__ pi,
    const float* __restrict__ cb,
    float* __restrict__ outq, float* __restrict__ outidx) {
  int r = blockIdx.x;
  int t = threadIdx.x;
  __shared__ int sidx;
  if (t < 64) {
    float v  = pv[(size_t)r * 64 + t];
    int   id = pi[(size_t)r * 64 + t];
#pragma unroll
    for (int o = 32; o >= 1; o >>= 1) {
      float ov = __shfl_xor(v, o);
      int   oi = __shfl_xor(id, o);
      if (ov < v || (ov == v && oi < id)) { v = ov; id = oi; }  // lex-min = first occurrence
    }
    if (t == 0) sidx = id;
  }
  __syncthreads();
  int id = sidx;
  const float4* src = (const float4*)(cb + (size_t)id * C);
  float4*       dst = (float4*)(outq + (size_t)r * C);
  dst[t] = src[t];  // 128 threads x 16B = 512 floats
  if (t == 0) outidx[r] = (float)id;
}

// ---------------- fused per-(window, head) attention ------------------------
__global__ __launch_bounds__(256) void attn_kernel(
    const float* __restrict__ qkv,   // chunk-local windowed rows x 1536
    const float* __restrict__ rpb,   // (225, 8)
    float* __restrict__ o,           // global windowed rows x 512
    int winOff, int shift) {
  int wl = blockIdx.x;  // window within chunk
  int h  = blockIdx.y;
  int t  = threadIdx.x;
  __shared__ float q[64][64], k[64][64], v[64][64], pT[64][64];  // 64 KiB

  const float* base = qkv + (size_t)wl * 64 * 1536 + h * 64;
#pragma unroll
  for (int rep = 0; rep < 4; rep++) {
    int f = t + rep * 256;
    int i = f >> 4, dq = (f & 15) * 4;
    const float* rowp = base + (size_t)i * 1536 + dq;
    float4 qv = *(const float4*)(rowp);
    float4 kv = *(const float4*)(rowp + 512);
    float4 vv = *(const float4*)(rowp + 1024);
    q[i][dq] = qv.x * 0.125f; q[i][dq + 1] = qv.y * 0.125f;
    q[i][dq + 2] = qv.z * 0.125f; q[i][dq + 3] = qv.w * 0.125f;
    *(float4*)&k[i][dq] = kv;
    *(float4*)&v[i][dq] = vv;
  }
  __syncthreads();

  int i  = t >> 2;       // score row
  int jg = t & 3;        // col group (16 cols each)
  int wim = (winOff + wl) & 15;
  int wy = wim >> 2, wx = wim & 3;
  int iy = i >> 3, ix = i & 7;

  float qreg[64];
#pragma unroll
  for (int d = 0; d < 64; d += 4) *(float4*)&qreg[d] = *(float4*)&q[i][d];

  int ci = 0;
  if (shift) ci = region(wy * 8 + iy) * 3 + region(wx * 8 + ix);

  float sc[16];
#pragma unroll
  for (int jj = 0; jj < 16; jj++) {
    int j = jg * 16 + jj;
    float s = 0.f;
#pragma unroll
    for (int d = 0; d < 64; d += 4) {
      float4 kv = *(float4*)&k[j][d];
      s = fmaf(qreg[d], kv.x, s);
      s = fmaf(qreg[d + 1], kv.y, s);
      s = fmaf(qreg[d + 2], kv.z, s);
      s = fmaf(qreg[d + 3], kv.w, s);
    }
    int jy = j >> 3, jx = j & 7;
    s += rpb[((iy - jy + 7) * 15 + (ix - jx + 7)) * 8 + h];
    if (shift) {
      int cj = region(wy * 8 + jy) * 3 + region(wx * 8 + jx);
      if (ci != cj) s -= 100.0f;
    }
    sc[jj] = s;
  }
  // softmax over the 64 cols of row i (4 threads x 16 vals)
  float mx = sc[0];
#pragma unroll
  for (int jj = 1; jj < 16; jj++) mx = fmaxf(mx, sc[jj]);
  mx = fmaxf(mx, __shfl_xor(mx, 1));
  mx = fmaxf(mx, __shfl_xor(mx, 2));
  float sum = 0.f;
#pragma unroll
  for (int jj = 0; jj < 16; jj++) { sc[jj] = expf(sc[jj] - mx); sum += sc[jj]; }
  sum += __shfl_xor(sum, 1);
  sum += __shfl_xor(sum, 2);
  float inv = 1.0f / sum;
#pragma unroll
  for (int jj = 0; jj < 16; jj++) pT[jg * 16 + jj][i] = sc[jj] * inv;
  __syncthreads();

  // PV: thread computes o[i][jg*16 .. +15]
  float accv[16];
#pragma unroll
  for (int dd = 0; dd < 16; dd++) accv[dd] = 0.f;
  for (int j = 0; j < 64; j++) {
    float pij = pT[j][i];
#pragma unroll
    for (int dd = 0; dd < 16; dd += 4) {
      float4 vv = *(float4*)&v[j][jg * 16 + dd];
      accv[dd]     = fmaf(pij, vv.x, accv[dd]);
      accv[dd + 1] = fmaf(pij, vv.y, accv[dd + 1]);
      accv[dd + 2] = fmaf(pij, vv.z, accv[dd + 2]);
      accv[dd + 3] = fmaf(pij, vv.w, accv[dd + 3]);
    }
  }
  size_t orow = (size_t)(winOff + wl) * 64 + i;
  float* od = o + orow * 512 + h * 64 + jg * 16;
#pragma unroll
  for (int dd = 0; dd < 16; dd += 4) *(float4*)&od[dd] = *(float4*)&accv[dd];
}

}  // namespace

extern "C" void kernel_launch(void* const* d_in, const int* in_sizes, int n_in,
                              void* d_out, int out_size, void* d_ws, size_t ws_size,
                              hipStream_t stream) {
  const float* x_in = (const float*)d_in[0];
  const float* n1g  = (const float*)d_in[1];
  const float* n1b  = (const float*)d_in[2];
  const float* qkvw = (const float*)d_in[3];
  const float* qkvb = (const float*)d_in[4];
  const float* rpb  = (const float*)d_in[5];
  const float* pw   = (const float*)d_in[6];
  const float* pb   = (const float*)d_in[7];
  const float* n2g  = (const float*)d_in[8];
  const float* n2b  = (const float*)d_in[9];
  const float* f1w  = (const float*)d_in[10];
  const float* f1b  = (const float*)d_in[11];
  const float* f2w  = (const float*)d_in[12];
  const float* f2b  = (const float*)d_in[13];
  const float* cb   = (const float*)d_in[14];

  float* outq   = (float*)d_out;
  float* outidx = outq + 16777216;        // 32768 idx values written as float
  float* Abuf = (float*)d_ws;                              // 64 MiB: residual stream x
  float* Cbuf = (float*)((char*)d_ws + 67108864);          // 48 MiB chunk scratch
  float* Bbuf = outq;                                      // reuse quant region as scratch

  for (int blk = 0; blk < 2; blk++) {
    const float* xcur = blk ? (const float*)Abuf : x_in;
    int shift = blk ? 4 : 0;

    // LN1 + shift + window partition -> Bbuf (windowed rows)
    ln_kernel<<<8192, 256, 0, stream>>>(xcur, Bbuf, n1g + blk * 512, n1b + blk * 512, shift, 1);

    // qkv GEMM + attention, 4 chunks of 8192 rows (128 windows)
    for (int ch = 0; ch < 4; ch++) {
      int r0 = ch * 8192;
      gemm_bias_kernel<0><<<dim3(64, 24), 256, 0, stream>>>(
          Bbuf + (size_t)r0 * 512, 512, qkvw + (size_t)blk * 512 * 1536, 1536,
          qkvb + blk * 1536, Cbuf, 1536, 512);
      attn_kernel<<<dim3(128, 8), 256, 0, stream>>>(
          Cbuf, rpb + blk * 1800, Bbuf, r0 / 64, shift);
    }

    // proj + window reverse + unshift + residual -> Abuf
    gemm_resid_kernel<true><<<dim3(256, 8), 256, 0, stream>>>(
        Bbuf, 512, pw + (size_t)blk * 512 * 512, 512, pb + blk * 512,
        Abuf, 512, 512, blk ? (const float*)Abuf : x_in, shift, 0);

    // LN2 -> Bbuf (identity row order)
    ln_kernel<<<8192, 256, 0, stream>>>(Abuf, Bbuf, n2g + blk * 512, n2b + blk * 512, 0, 0);

    // MLP: fc1+GELU then fc2+residual, 8 chunks of 4096 rows
    for (int ch = 0; ch < 8; ch++) {
      int r0 = ch * 4096;
      gemm_bias_kernel<1><<<dim3(32, 32), 256, 0, stream>>>(
          Bbuf + (size_t)r0 * 512, 512, f1w + (size_t)blk * 512 * 2048, 2048,
          f1b + blk * 2048, Cbuf, 2048, 512);
      gemm_resid_kernel<false><<<dim3(32, 8), 256, 0, stream>>>(
          Cbuf, 2048, f2w + (size_t)blk * 2048 * 512, 512, f2b + blk * 512,
          Abuf, 512, 2048, Abuf, 0, r0);
    }
  }

  // ---- VQ: d = |x|^2 - 2 x.c + |c|^2, argmin over 4096 codes ----
  float* pv = Cbuf;                       // 32768 x 64 partial min values
  int*   pi = (int*)(Cbuf + 2097152);     // 32768 x 64 partial min indices
  float* x2 = Cbuf + 4194304;
  float* c2 = x2 + 32768;
  rowss_kernel<<<8192, 256, 0, stream>>>(Abuf, x2, 32768);
  rowss_kernel<<<1024, 256, 0, stream>>>(cb, c2, 4096);
  gemm_dist_kernel<<<dim3(256, 64), 256, 0, stream>>>(
      Abuf, 512, cb, 512, x2, c2, pv, pi, 512);
  vq_out_kernel<<<32768, 128, 0, stream>>>(pv, pi, cb, outq, outidx);
}

// Round 6
// 4937.185 us; speedup vs baseline: 1.7530x; 1.7530x over previous
//
#include <hip/hip_runtime.h>
#include <math.h>

#define DEV __device__ __forceinline__

typedef __attribute__((ext_vector_type(8))) _Float16 f16x8;
typedef __attribute__((ext_vector_type(8))) short short8;
typedef __attribute__((ext_vector_type(4))) float f32x4;

namespace {

constexpr int C = 512;
constexpr int ROWS = 32768;   // B * L
constexpr float LSCALE = 2048.0f;        // lo-plane pre-scale (2^11)
constexpr float LINV   = 1.0f / 2048.0f;
constexpr float F16MIN = 6.1035156e-5f;  // fp16 min normal

// fp32 -> fp16 hi/lo split. h = RTN(x) (flushed to 0 below normal range),
// l = RTN((x - h) * 2^11). Ensures all MFMA inputs are 0 or normal fp16.
DEV void f2hsplit(float x, short& hs, short& ls) {
  _Float16 h = (_Float16)x;
  float hf = (float)h;
  if (fabsf(hf) < F16MIN) { h = (_Float16)0.0f; hf = 0.f; }
  _Float16 l = (_Float16)((x - hf) * LSCALE);
  if (fabsf((float)l) < F16MIN) l = (_Float16)0.0f;
  hs = __builtin_bit_cast(short, h);
  ls = __builtin_bit_cast(short, l);
}

DEV unsigned umn(unsigned a, unsigned b) { return a < b ? a : b; }
DEV unsigned umx(unsigned a, unsigned b) { return a > b ? a : b; }

// monotone key: high 20 bits = sign-flipped fp32 distance, low 12 = col idx.
DEV unsigned packkey(float d, int col) {
  unsigned u = __builtin_bit_cast(unsigned, d);
  u = (u & 0x80000000u) ? ~u : (u | 0x80000000u);
  return (u & 0xFFFFF000u) | (unsigned)col;
}
DEV float unpackd(unsigned k) {
  unsigned u = (k & 0x80000000u) ? (k ^ 0x80000000u) : ~k;
  return __builtin_bit_cast(float, u);
}

// windowed row r -> flat row in (b, y, x) order, for roll by `shift`.
DEV int rowmap(int r, int shift) {
  int b  = r >> 10;
  int w  = (r >> 6) & 15;
  int wy = w >> 2, wx = w & 3;
  int ii = r & 63;
  int iy = ii >> 3, ix = ii & 7;
  int y = (wy * 8 + iy + shift) & 31;
  int x = (wx * 8 + ix + shift) & 31;
  return (b << 10) + (y << 5) + x;
}

DEV int region(int y) { return (y < 24) ? 0 : ((y < 28) ? 1 : 2); }

typedef __attribute__((address_space(1))) const unsigned int gu32;
typedef __attribute__((address_space(3))) unsigned int lu32;
DEV void gload16(const void* g, void* l) {
  __builtin_amdgcn_global_load_lds((gu32*)g, (lu32*)l, 16, 0, 0);
}

// ---------------- LayerNorm -> fp16 hi/lo planes ---------------------------
__global__ __launch_bounds__(256) void ln_split_kernel(
    const float* __restrict__ src, short* __restrict__ Hp, short* __restrict__ Lp,
    const float* __restrict__ g, const float* __restrict__ b,
    int shift, int windowed) {
  int wid  = (blockIdx.x * 256 + threadIdx.x) >> 6;
  int lane = threadIdx.x & 63;
  if (wid >= ROWS) return;
  int srcRow = windowed ? rowmap(wid, shift) : wid;
  const float* s = src + (size_t)srcRow * C + lane * 8;
  float v[8];
  *(float4*)(v)     = *(const float4*)(s);
  *(float4*)(v + 4) = *(const float4*)(s + 4);
  float sum = 0.f;
#pragma unroll
  for (int j = 0; j < 8; j++) sum += v[j];
#pragma unroll
  for (int o = 32; o >= 1; o >>= 1) sum += __shfl_xor(sum, o);
  float mu = sum * (1.0f / 512.0f);
  float vs = 0.f;
#pragma unroll
  for (int j = 0; j < 8; j++) { float d = v[j] - mu; vs += d * d; }
#pragma unroll
  for (int o = 32; o >= 1; o >>= 1) vs += __shfl_xor(vs, o);
  float rs = rsqrtf(vs * (1.0f / 512.0f) + 1e-5f);
  float gg[8], bb[8];
  *(float4*)gg       = *(const float4*)&g[lane * 8];
  *(float4*)(gg + 4) = *(const float4*)&g[lane * 8 + 4];
  *(float4*)bb       = *(const float4*)&b[lane * 8];
  *(float4*)(bb + 4) = *(const float4*)&b[lane * 8 + 4];
  short8 hv, lv;
#pragma unroll
  for (int j = 0; j < 8; j++) {
    float o8 = (v[j] - mu) * rs * gg[j] + bb[j];
    short hh, ll;
    f2hsplit(o8, hh, ll);
    hv[j] = hh; lv[j] = ll;
  }
  *(short8*)&Hp[(size_t)wid * C + lane * 8] = hv;
  *(short8*)&Lp[(size_t)wid * C + lane * 8] = lv;
}

// ---------------- row sum of squares (codebook) ----------------------------
__global__ __launch_bounds__(256) void rowss_kernel(
    const float* __restrict__ src, float* __restrict__ dst, int nrows) {
  int wid  = (blockIdx.x * 256 + threadIdx.x) >> 6;
  int lane = threadIdx.x & 63;
  if (wid >= nrows) return;
  const float* s = src + (size_t)wid * C + lane * 8;
  float4 a  = *(const float4*)s;
  float4 b4 = *(const float4*)(s + 4);
  float sum = a.x*a.x + a.y*a.y + a.z*a.z + a.w*a.w
            + b4.x*b4.x + b4.y*b4.y + b4.z*b4.z + b4.w*b4.w;
#pragma unroll
  for (int o = 32; o >= 1; o >>= 1) sum += __shfl_xor(sum, o);
  if (lane == 0) dst[wid] = sum;
}

// ---------------- fp32 -> hi/lo split (whole tensor) -----------------------
__global__ __launch_bounds__(256) void split_kernel(
    const float* __restrict__ x, short* __restrict__ Hp, short* __restrict__ Lp) {
  size_t i = ((size_t)blockIdx.x * 256 + threadIdx.x) * 8;
  float4 a  = *(const float4*)&x[i];
  float4 b4 = *(const float4*)&x[i + 4];
  float v[8] = {a.x, a.y, a.z, a.w, b4.x, b4.y, b4.z, b4.w};
  short8 hv, lv;
#pragma unroll
  for (int j = 0; j < 8; j++) {
    short hh, ll;
    f2hsplit(v[j], hh, ll);
    hv[j] = hh; lv[j] = ll;
  }
  *(short8*)&Hp[i] = hv;
  *(short8*)&Lp[i] = lv;
}

// ---------------- weight transpose + split: W(K,N) -> H/L (N,K) ------------
__global__ __launch_bounds__(256) void wconvT_kernel(
    const float* __restrict__ W, short* __restrict__ Hp, short* __restrict__ Lp,
    int K, int N) {
  __shared__ float t[32][33];
  int tx = threadIdx.x, ty = threadIdx.y;
  int n0 = blockIdx.x * 32, k0 = blockIdx.y * 32;
#pragma unroll
  for (int r = 0; r < 4; r++) {
    int k = ty + r * 8;
    t[k][tx] = W[(size_t)(k0 + k) * N + n0 + tx];
  }
  __syncthreads();
#pragma unroll
  for (int r = 0; r < 4; r++) {
    int n = ty + r * 8;
    short h, l;
    f2hsplit(t[tx][n], h, l);
    Hp[(size_t)(n0 + n) * K + k0 + tx] = h;
    Lp[(size_t)(n0 + n) * K + k0 + tx] = l;
  }
}

// ---------------- codebook split (already N-major) -------------------------
__global__ __launch_bounds__(256) void wconv_kernel(
    const float* __restrict__ W, short* __restrict__ Hp, short* __restrict__ Lp) {
  size_t i = ((size_t)blockIdx.x * 256 + threadIdx.x) * 4;
  float4 a = *(const float4*)&W[i];
  float v[4] = {a.x, a.y, a.z, a.w};
  short hv[4], lv[4];
#pragma unroll
  for (int j = 0; j < 4; j++) f2hsplit(v[j], hv[j], lv[j]);
  *(short4*)&Hp[i] = *(short4*)hv;
  *(short4*)&Lp[i] = *(short4*)lv;
}

// ---------------- fp16-pair MFMA GEMM, 128x128 tile, BK=32 -----------------
// A planes [M][K], B planes [N][K]; C = A * B^T (+ epilogue).
// acc = accH(h*h) + 2^-11 * accL(h*lw + la*h); la/lw are pre-scaled by 2^11.
// EPI: 0 = fp32 out+bias (qkv); 1 = gelu -> hi/lo planes (fc1);
//      2 = +bias+resid fp32 (proj/fc2); 3 = VQ top-2-per-tile packed keys
template <int EPI>
__global__ __launch_bounds__(256) void mgemm(
    const short* __restrict__ Ah, const short* __restrict__ Al,
    const short* __restrict__ Bh, const short* __restrict__ Bl,
    const int K, const float* __restrict__ bias,
    float* __restrict__ outF, short* __restrict__ outH, short* __restrict__ outL,
    const int ldo,
    const float* __restrict__ resid, const int rowOff, const int perm, const int shift,
    const float* __restrict__ c2, unsigned* __restrict__ pk) {
  __shared__ short lds[16384];   // Ah | Al | Bh | Bl tiles, each 128x32 fp16
  const int m0 = blockIdx.x * 128, n0 = blockIdx.y * 128;
  const int t  = threadIdx.x;
  const int wv = t >> 6, ln = t & 63;
  const int wr = (wv >> 1) * 64, wc = (wv & 1) * 64;
  const int l15 = ln & 15, l4 = ln >> 4;

  f32x4 accH[4][4], accL[4][4];
#pragma unroll
  for (int mf = 0; mf < 4; mf++)
#pragma unroll
    for (int nf = 0; nf < 4; nf++) {
      accH[mf][nf] = (f32x4){0.f, 0.f, 0.f, 0.f};
      accL[mf][nf] = (f32x4){0.f, 0.f, 0.f, 0.f};
    }

  const int srow = ln >> 2;                              // row within 16-row chunk
  const int scol = ((ln & 3) ^ ((ln >> 3) & 3)) * 8;     // pre-swizzled source chunk

  short* As_h = lds;
  short* As_l = lds + 4096;
  short* Bs_h = lds + 8192;
  short* Bs_l = lds + 12288;

  auto frag = [&](const short* lt, int rbase) -> f16x8 {
    int r = rbase + l15;
    int kc = l4 ^ ((r >> 1) & 3);
    return *(const f16x8*)(lt + r * 32 + kc * 8);
  };

  for (int k0 = 0; k0 < K; k0 += 32) {
#pragma unroll
    for (int q = 0; q < 2; q++) {
      int ci = wv * 2 + q;
      size_t ra = (size_t)(m0 + ci * 16 + srow) * K + k0 + scol;
      size_t rb = (size_t)(n0 + ci * 16 + srow) * K + k0 + scol;
      gload16(Ah + ra, As_h + ci * 512);
      gload16(Al + ra, As_l + ci * 512);
      gload16(Bh + rb, Bs_h + ci * 512);
      gload16(Bl + rb, Bs_l + ci * 512);
    }
    __syncthreads();
    f16x8 ah[4], bh4[4], bl4[4];
#pragma unroll
    for (int mf = 0; mf < 4; mf++) ah[mf] = frag(As_h, wr + mf * 16);
#pragma unroll
    for (int nf = 0; nf < 4; nf++) bh4[nf] = frag(Bs_h, wc + nf * 16);
#pragma unroll
    for (int mf = 0; mf < 4; mf++)
#pragma unroll
      for (int nf = 0; nf < 4; nf++)
        accH[mf][nf] = __builtin_amdgcn_mfma_f32_16x16x32_f16(ah[mf], bh4[nf], accH[mf][nf], 0, 0, 0);
#pragma unroll
    for (int nf = 0; nf < 4; nf++) bl4[nf] = frag(Bs_l, wc + nf * 16);
#pragma unroll
    for (int mf = 0; mf < 4; mf++)
#pragma unroll
      for (int nf = 0; nf < 4; nf++)
        accL[mf][nf] = __builtin_amdgcn_mfma_f32_16x16x32_f16(ah[mf], bl4[nf], accL[mf][nf], 0, 0, 0);
#pragma unroll
    for (int mf = 0; mf < 4; mf++) {
      f16x8 al = frag(As_l, wr + mf * 16);
#pragma unroll
      for (int nf = 0; nf < 4; nf++)
        accL[mf][nf] = __builtin_amdgcn_mfma_f32_16x16x32_f16(al, bh4[nf], accL[mf][nf], 0, 0, 0);
    }
    __syncthreads();
  }

  // combine hi/lo accumulators
  f32x4 acc[4][4];
#pragma unroll
  for (int mf = 0; mf < 4; mf++)
#pragma unroll
    for (int nf = 0; nf < 4; nf++)
#pragma unroll
      for (int r = 0; r < 4; r++)
        acc[mf][nf][r] = fmaf(accL[mf][nf][r], LINV, accH[mf][nf][r]);

  if (EPI == 0) {
#pragma unroll
    for (int mf = 0; mf < 4; mf++)
#pragma unroll
      for (int r = 0; r < 4; r++) {
        int row = m0 + wr + mf * 16 + l4 * 4 + r;
        float* op = outF + (size_t)row * ldo;
#pragma unroll
        for (int nf = 0; nf < 4; nf++) {
          int col = n0 + wc + nf * 16 + l15;
          op[col] = acc[mf][nf][r] + bias[col];
        }
      }
  } else if (EPI == 1) {
#pragma unroll
    for (int mf = 0; mf < 4; mf++)
#pragma unroll
      for (int r = 0; r < 4; r++) {
        int row = m0 + wr + mf * 16 + l4 * 4 + r;
#pragma unroll
        for (int nf = 0; nf < 4; nf++) {
          int col = n0 + wc + nf * 16 + l15;
          float v = acc[mf][nf][r] + bias[col];
          v = 0.5f * v * (1.0f + erff(v * 0.70710678118654752f));
          short h, l;
          f2hsplit(v, h, l);
          outH[(size_t)row * ldo + col] = h;
          outL[(size_t)row * ldo + col] = l;
        }
      }
  } else if (EPI == 2) {
#pragma unroll
    for (int mf = 0; mf < 4; mf++)
#pragma unroll
      for (int r = 0; r < 4; r++) {
        int row = m0 + wr + mf * 16 + l4 * 4 + r;
        int orow = perm ? rowmap(row, shift) : (row + rowOff);
        const float* rp = resid + (size_t)orow * ldo;
        float* op = outF + (size_t)orow * ldo;
#pragma unroll
        for (int nf = 0; nf < 4; nf++) {
          int col = n0 + wc + nf * 16 + l15;
          op[col] = rp[col] + acc[mf][nf][r] + bias[col];
        }
      }
  } else {  // EPI == 3: top-2 per 128-col tile, packed keys
    unsigned* hk = (unsigned*)(void*)lds;   // [128 rows][2 halves][2 entries]
#pragma unroll
    for (int mf = 0; mf < 4; mf++)
#pragma unroll
      for (int r = 0; r < 4; r++) {
        int wrow = wr + mf * 16 + l4 * 4 + r;
        unsigned k1 = 0xFFFFFFFFu, k2 = 0xFFFFFFFFu;
#pragma unroll
        for (int nf = 0; nf < 4; nf++) {
          int col = n0 + wc + nf * 16 + l15;
          float d = c2[col] - 2.0f * acc[mf][nf][r];
          unsigned kk = packkey(d, col);
          if (kk < k1) { k2 = k1; k1 = kk; }
          else if (kk < k2) { k2 = kk; }
        }
#pragma unroll
        for (int o = 1; o <= 8; o <<= 1) {
          unsigned b1 = (unsigned)__shfl_xor((int)k1, o);
          unsigned b2 = (unsigned)__shfl_xor((int)k2, o);
          unsigned m1 = umn(k1, b1);
          unsigned m2 = umn(umx(k1, b1), umn(k2, b2));
          k1 = m1; k2 = m2;
        }
        if (l15 == 0) {
          hk[wrow * 4 + (wv & 1) * 2 + 0] = k1;
          hk[wrow * 4 + (wv & 1) * 2 + 1] = k2;
        }
      }
    __syncthreads();
    if (t < 128) {
      unsigned a1 = hk[t * 4 + 0], a2 = hk[t * 4 + 1];
      unsigned b1 = hk[t * 4 + 2], b2 = hk[t * 4 + 3];
      unsigned m1 = umn(a1, b1);
      unsigned m2 = umn(umx(a1, b1), umn(a2, b2));
      size_t base = (size_t)(m0 + t) * 64 + blockIdx.y * 2;
      pk[base + 0] = m1;
      pk[base + 1] = m2;
    }
  }
}

// ---------------- candidate select + exact fp32 rescore + gather -----------
__global__ __launch_bounds__(256) void vq_out_kernel(
    const unsigned* __restrict__ pk, const float* __restrict__ x,
    const float* __restrict__ cb,
    float* __restrict__ outq, float* __restrict__ outidx) {
  int r = blockIdx.x * 4 + (threadIdx.x >> 6);
  int lane = threadIdx.x & 63;
  unsigned key = pk[(size_t)r * 64 + lane];
  unsigned kmin = key;
#pragma unroll
  for (int o = 32; o >= 1; o >>= 1) kmin = umn(kmin, (unsigned)__shfl_xor((int)kmin, o));
  float dmin = unpackd(kmin);
  unsigned long long mask = __ballot(unpackd(key) <= dmin + 2.0f);

  const float* xr = x + (size_t)r * C + lane * 8;
  float4 xa = *(const float4*)xr;
  float4 xb = *(const float4*)(xr + 4);

  float bestd = 3.4e38f;
  int   besti = 0x7fffffff;
  while (mask) {
    int l = __ffsll(mask) - 1;
    mask &= mask - 1;
    int col = ((unsigned)__shfl((int)key, l)) & 0xFFFu;
    const float* cr = cb + (size_t)col * C + lane * 8;
    float4 ca = *(const float4*)cr;
    float4 cb4 = *(const float4*)(cr + 4);
    float s = 0.f;
    s = fmaf(ca.x, ca.x - 2.f * xa.x, s);
    s = fmaf(ca.y, ca.y - 2.f * xa.y, s);
    s = fmaf(ca.z, ca.z - 2.f * xa.z, s);
    s = fmaf(ca.w, ca.w - 2.f * xa.w, s);
    s = fmaf(cb4.x, cb4.x - 2.f * xb.x, s);
    s = fmaf(cb4.y, cb4.y - 2.f * xb.y, s);
    s = fmaf(cb4.z, cb4.z - 2.f * xb.z, s);
    s = fmaf(cb4.w, cb4.w - 2.f * xb.w, s);
#pragma unroll
    for (int o = 32; o >= 1; o >>= 1) s += __shfl_xor(s, o);
    if (s < bestd || (s == bestd && col < besti)) { bestd = s; besti = col; }
  }
  const float4* src = (const float4*)(cb + (size_t)besti * C + lane * 8);
  float4*       dst = (float4*)(outq + (size_t)r * C + lane * 8);
  dst[0] = src[0];
  dst[1] = src[1];
  if (lane == 0) outidx[r] = (float)besti;
}

// ---------------- fused per-(window, head) attention (fp32) ----------------
__global__ __launch_bounds__(256) void attn_kernel(
    const float* __restrict__ qkv,   // chunk-local windowed rows x 1536
    const float* __restrict__ rpb,   // (225, 8)
    short* __restrict__ Hout, short* __restrict__ Lout,  // global windowed rows x 512
    int winOff, int shift) {
  int wl = blockIdx.x;
  int h  = blockIdx.y;
  int t  = threadIdx.x;
  __shared__ float q[64][64], k[64][64], v[64][64], pT[64][64];

  const float* base = qkv + (size_t)wl * 64 * 1536 + h * 64;
#pragma unroll
  for (int rep = 0; rep < 4; rep++) {
    int f = t + rep * 256;
    int i = f >> 4, dq = (f & 15) * 4;
    const float* rowp = base + (size_t)i * 1536 + dq;
    float4 qv = *(const float4*)(rowp);
    float4 kv = *(const float4*)(rowp + 512);
    float4 vv = *(const float4*)(rowp + 1024);
    q[i][dq] = qv.x * 0.125f; q[i][dq + 1] = qv.y * 0.125f;
    q[i][dq + 2] = qv.z * 0.125f; q[i][dq + 3] = qv.w * 0.125f;
    *(float4*)&k[i][dq] = kv;
    *(float4*)&v[i][dq] = vv;
  }
  __syncthreads();

  int i  = t >> 2;
  int jg = t & 3;
  int wim = (winOff + wl) & 15;
  int wy = wim >> 2, wx = wim & 3;
  int iy = i >> 3, ix = i & 7;

  float qreg[64];
#pragma unroll
  for (int d = 0; d < 64; d += 4) *(float4*)&qreg[d] = *(float4*)&q[i][d];

  int ci = 0;
  if (shift) ci = region(wy * 8 + iy) * 3 + region(wx * 8 + ix);

  float sc[16];
#pragma unroll
  for (int jj = 0; jj < 16; jj++) {
    int j = jg * 16 + jj;
    float s = 0.f;
#pragma unroll
    for (int d = 0; d < 64; d += 4) {
      float4 kv = *(float4*)&k[j][d];
      s = fmaf(qreg[d], kv.x, s);
      s = fmaf(qreg[d + 1], kv.y, s);
      s = fmaf(qreg[d + 2], kv.z, s);
      s = fmaf(qreg[d + 3], kv.w, s);
    }
    int jy = j >> 3, jx = j & 7;
    s += rpb[((iy - jy + 7) * 15 + (ix - jx + 7)) * 8 + h];
    if (shift) {
      int cj = region(wy * 8 + jy) * 3 + region(wx * 8 + jx);
      if (ci != cj) s -= 100.0f;
    }
    sc[jj] = s;
  }
  float mx = sc[0];
#pragma unroll
  for (int jj = 1; jj < 16; jj++) mx = fmaxf(mx, sc[jj]);
  mx = fmaxf(mx, __shfl_xor(mx, 1));
  mx = fmaxf(mx, __shfl_xor(mx, 2));
  float sum = 0.f;
#pragma unroll
  for (int jj = 0; jj < 16; jj++) { sc[jj] = expf(sc[jj] - mx); sum += sc[jj]; }
  sum += __shfl_xor(sum, 1);
  sum += __shfl_xor(sum, 2);
  float inv = 1.0f / sum;
#pragma unroll
  for (int jj = 0; jj < 16; jj++) pT[jg * 16 + jj][i] = sc[jj] * inv;
  __syncthreads();

  float accv[16];
#pragma unroll
  for (int dd = 0; dd < 16; dd++) accv[dd] = 0.f;
  for (int j = 0; j < 64; j++) {
    float pij = pT[j][i];
#pragma unroll
    for (int dd = 0; dd < 16; dd += 4) {
      float4 vv = *(float4*)&v[j][jg * 16 + dd];
      accv[dd]     = fmaf(pij, vv.x, accv[dd]);
      accv[dd + 1] = fmaf(pij, vv.y, accv[dd + 1]);
      accv[dd + 2] = fmaf(pij, vv.z, accv[dd + 2]);
      accv[dd + 3] = fmaf(pij, vv.w, accv[dd + 3]);
    }
  }
  size_t obase = ((size_t)(winOff + wl) * 64 + i) * 512 + h * 64 + jg * 16;
  short8 hv, lv;
#pragma unroll
  for (int half = 0; half < 2; half++) {
#pragma unroll
    for (int j = 0; j < 8; j++) {
      short hh, ll;
      f2hsplit(accv[half * 8 + j], hh, ll);
      hv[j] = hh; lv[j] = ll;
    }
    *(short8*)&Hout[obase + half * 8] = hv;
    *(short8*)&Lout[obase + half * 8] = lv;
  }
}

}  // namespace

extern "C" void kernel_launch(void* const* d_in, const int* in_sizes, int n_in,
                              void* d_out, int out_size, void* d_ws, size_t ws_size,
                              hipStream_t stream) {
  const float* x_in = (const float*)d_in[0];
  const float* n1g  = (const float*)d_in[1];
  const float* n1b  = (const float*)d_in[2];
  const float* qkvw = (const float*)d_in[3];
  const float* qkvb = (const float*)d_in[4];
  const float* rpb  = (const float*)d_in[5];
  const float* pw   = (const float*)d_in[6];
  const float* pb   = (const float*)d_in[7];
  const float* n2g  = (const float*)d_in[8];
  const float* n2b  = (const float*)d_in[9];
  const float* f1w  = (const float*)d_in[10];
  const float* f1b  = (const float*)d_in[11];
  const float* f2w  = (const float*)d_in[12];
  const float* f2b_ = (const float*)d_in[13];
  const float* cb   = (const float*)d_in[14];

  float* outq   = (float*)d_out;
  float* outidx = outq + 16777216;
  short* Hbuf = (short*)d_out;                 // hi plane: first 32MB of outq
  short* Lbuf = Hbuf + (size_t)ROWS * 512;     // lo plane: second 32MB

  char* ws = (char*)d_ws;
  float* Abuf = (float*)ws;                               // 64MiB residual stream
  short* Wb   = (short*)(ws + ((size_t)64 << 20));        // 32MiB weight planes
  char*  Cbuf = ws + ((size_t)96 << 20);                  // chunk scratch
  const int Rrows = (ws_size >= ((size_t)130 << 20)) ? 4096 : 2048;

  const int SZ_QKV = 512 * 1536, SZ_P = 512 * 512, SZ_F1 = 512 * 2048, SZ_F2 = 2048 * 512;
  const int PB = (SZ_QKV + SZ_P + SZ_F1 + SZ_F2) * 2;
  short* cbH = Wb + (size_t)2 * PB;
  short* cbL = cbH + 4096 * 512;

  // ---- one-time (per launch) weight transpose + split ----
  for (int blk = 0; blk < 2; blk++) {
    short* base = Wb + (size_t)blk * PB;
    short* qH = base;          short* qL = qH + SZ_QKV;
    short* pH = qL + SZ_QKV;   short* pL = pH + SZ_P;
    short* f1H = pL + SZ_P;    short* f1L = f1H + SZ_F1;
    short* f2H = f1L + SZ_F1;  short* f2L = f2H + SZ_F2;
    wconvT_kernel<<<dim3(48, 16), dim3(32, 8), 0, stream>>>(qkvw + (size_t)blk * SZ_QKV, qH, qL, 512, 1536);
    wconvT_kernel<<<dim3(16, 16), dim3(32, 8), 0, stream>>>(pw + (size_t)blk * SZ_P, pH, pL, 512, 512);
    wconvT_kernel<<<dim3(64, 16), dim3(32, 8), 0, stream>>>(f1w + (size_t)blk * SZ_F1, f1H, f1L, 512, 2048);
    wconvT_kernel<<<dim3(16, 64), dim3(32, 8), 0, stream>>>(f2w + (size_t)blk * SZ_F2, f2H, f2L, 2048, 512);
  }
  wconv_kernel<<<2048, 256, 0, stream>>>(cb, cbH, cbL);

  const int nch = ROWS / Rrows;
  for (int blk = 0; blk < 2; blk++) {
    short* base = Wb + (size_t)blk * PB;
    short* qH = base;          short* qL = qH + SZ_QKV;
    short* pH = qL + SZ_QKV;   short* pL = pH + SZ_P;
    short* f1H = pL + SZ_P;    short* f1L = f1H + SZ_F1;
    short* f2H = f1L + SZ_F1;  short* f2L = f2H + SZ_F2;
    const float* xcur = blk ? (const float*)Abuf : x_in;
    int shift = blk ? 4 : 0;

    // LN1 + shift + window partition -> hi/lo planes (windowed order)
    ln_split_kernel<<<8192, 256, 0, stream>>>(xcur, Hbuf, Lbuf, n1g + blk * 512, n1b + blk * 512, shift, 1);

    // qkv GEMM (fp32 out) + attention (writes planes back in place)
    float* Cq = (float*)Cbuf;
    for (int ch = 0; ch < nch; ch++) {
      int r0 = ch * Rrows;
      mgemm<0><<<dim3(Rrows / 128, 12), 256, 0, stream>>>(
          Hbuf + (size_t)r0 * 512, Lbuf + (size_t)r0 * 512, qH, qL, 512,
          qkvb + blk * 1536, Cq, nullptr, nullptr, 1536,
          nullptr, 0, 0, 0, nullptr, nullptr);
      attn_kernel<<<dim3(Rrows / 64, 8), 256, 0, stream>>>(
          Cq, rpb + blk * 1800, Hbuf, Lbuf, r0 >> 6, shift);
    }

    // proj + window reverse + unshift + residual -> Abuf (fp32)
    mgemm<2><<<dim3(256, 4), 256, 0, stream>>>(
        Hbuf, Lbuf, pH, pL, 512, pb + blk * 512,
        Abuf, nullptr, nullptr, 512,
        blk ? (const float*)Abuf : x_in, 0, 1, shift, nullptr, nullptr);

    // LN2 -> planes (identity order)
    ln_split_kernel<<<8192, 256, 0, stream>>>(Abuf, Hbuf, Lbuf, n2g + blk * 512, n2b + blk * 512, 0, 0);

    // MLP
    short* gh = (short*)Cbuf;
    short* gl = gh + (size_t)Rrows * 2048;
    for (int ch = 0; ch < nch; ch++) {
      int r0 = ch * Rrows;
      mgemm<1><<<dim3(Rrows / 128, 16), 256, 0, stream>>>(
          Hbuf + (size_t)r0 * 512, Lbuf + (size_t)r0 * 512, f1H, f1L, 512,
          f1b + blk * 2048, nullptr, gh, gl, 2048,
          nullptr, 0, 0, 0, nullptr, nullptr);
      mgemm<2><<<dim3(Rrows / 128, 4), 256, 0, stream>>>(
          gh, gl, f2H, f2L, 2048, f2b_ + blk * 512,
          Abuf, nullptr, nullptr, 512,
          Abuf, r0, 0, 0, nullptr, nullptr);
    }
  }

  // ---- VQ: approx top-2/tile via fp16-pair GEMM, exact fp32 rescore ----
  split_kernel<<<8192, 256, 0, stream>>>(Abuf, Hbuf, Lbuf);
  float*    c2  = (float*)Cbuf;                              // 16 KB
  unsigned* pkb = (unsigned*)(Cbuf + ((size_t)64 << 10));    // 8 MiB: 32768 x 64 keys
  rowss_kernel<<<1024, 256, 0, stream>>>(cb, c2, 4096);
  mgemm<3><<<dim3(256, 32), 256, 0, stream>>>(
      Hbuf, Lbuf, cbH, cbL, 512, nullptr,
      nullptr, nullptr, nullptr, 0,
      nullptr, 0, 0, 0, c2, pkb);
  vq_out_kernel<<<8192, 256, 0, stream>>>(pkb, Abuf, cb, outq, outidx);
}

// Round 7
// 3224.205 us; speedup vs baseline: 2.6843x; 1.5313x over previous
//
#include <hip/hip_runtime.h>
#include <math.h>

#define DEV __device__ __forceinline__

typedef __attribute__((ext_vector_type(8))) _Float16 f16x8;
typedef __attribute__((ext_vector_type(8))) short short8;
typedef __attribute__((ext_vector_type(4))) float f32x4;

namespace {

constexpr int C = 512;
constexpr int ROWS = 32768;   // B * L
constexpr float LSCALE = 2048.0f;        // lo-plane pre-scale (2^11)
constexpr float LINV   = 1.0f / 2048.0f;
constexpr float F16MIN = 6.1035156e-5f;  // fp16 min normal

// fp32 -> fp16 hi/lo split. h = RTN(x) (flushed to 0 below normal range),
// l = RTN((x - h) * 2^11). Ensures all MFMA inputs are 0 or normal fp16.
DEV void f2hsplit(float x, short& hs, short& ls) {
  _Float16 h = (_Float16)x;
  float hf = (float)h;
  if (fabsf(hf) < F16MIN) { h = (_Float16)0.0f; hf = 0.f; }
  _Float16 l = (_Float16)((x - hf) * LSCALE);
  if (fabsf((float)l) < F16MIN) l = (_Float16)0.0f;
  hs = __builtin_bit_cast(short, h);
  ls = __builtin_bit_cast(short, l);
}

DEV unsigned umn(unsigned a, unsigned b) { return a < b ? a : b; }
DEV unsigned umx(unsigned a, unsigned b) { return a > b ? a : b; }

// monotone key: high 20 bits = sign-flipped fp32 distance, low 12 = col idx.
DEV unsigned packkey(float d, int col) {
  unsigned u = __builtin_bit_cast(unsigned, d);
  u = (u & 0x80000000u) ? ~u : (u | 0x80000000u);
  return (u & 0xFFFFF000u) | (unsigned)col;
}
DEV float unpackd(unsigned k) {
  unsigned u = (k & 0x80000000u) ? (k ^ 0x80000000u) : ~k;
  return __builtin_bit_cast(float, u);
}

// windowed row r -> flat row in (b, y, x) order, for roll by `shift`.
DEV int rowmap(int r, int shift) {
  int b  = r >> 10;
  int w  = (r >> 6) & 15;
  int wy = w >> 2, wx = w & 3;
  int ii = r & 63;
  int iy = ii >> 3, ix = ii & 7;
  int y = (wy * 8 + iy + shift) & 31;
  int x = (wx * 8 + ix + shift) & 31;
  return (b << 10) + (y << 5) + x;
}

DEV int region(int y) { return (y < 24) ? 0 : ((y < 28) ? 1 : 2); }

typedef __attribute__((address_space(1))) const unsigned int gu32;
typedef __attribute__((address_space(3))) unsigned int lu32;
DEV void gload16(const void* g, void* l) {
  __builtin_amdgcn_global_load_lds((gu32*)g, (lu32*)l, 16, 0, 0);
}

// ---------------- LayerNorm -> fp16 hi/lo planes ---------------------------
__global__ __launch_bounds__(256) void ln_split_kernel(
    const float* __restrict__ src, short* __restrict__ Hp, short* __restrict__ Lp,
    const float* __restrict__ g, const float* __restrict__ b,
    int shift, int windowed) {
  int wid  = (blockIdx.x * 256 + threadIdx.x) >> 6;
  int lane = threadIdx.x & 63;
  if (wid >= ROWS) return;
  int srcRow = windowed ? rowmap(wid, shift) : wid;
  const float* s = src + (size_t)srcRow * C + lane * 8;
  float v[8];
  *(float4*)(v)     = *(const float4*)(s);
  *(float4*)(v + 4) = *(const float4*)(s + 4);
  float sum = 0.f;
#pragma unroll
  for (int j = 0; j < 8; j++) sum += v[j];
#pragma unroll
  for (int o = 32; o >= 1; o >>= 1) sum += __shfl_xor(sum, o);
  float mu = sum * (1.0f / 512.0f);
  float vs = 0.f;
#pragma unroll
  for (int j = 0; j < 8; j++) { float d = v[j] - mu; vs += d * d; }
#pragma unroll
  for (int o = 32; o >= 1; o >>= 1) vs += __shfl_xor(vs, o);
  float rs = rsqrtf(vs * (1.0f / 512.0f) + 1e-5f);
  float gg[8], bb[8];
  *(float4*)gg       = *(const float4*)&g[lane * 8];
  *(float4*)(gg + 4) = *(const float4*)&g[lane * 8 + 4];
  *(float4*)bb       = *(const float4*)&b[lane * 8];
  *(float4*)(bb + 4) = *(const float4*)&b[lane * 8 + 4];
  short8 hv, lv;
#pragma unroll
  for (int j = 0; j < 8; j++) {
    float o8 = (v[j] - mu) * rs * gg[j] + bb[j];
    short hh, ll;
    f2hsplit(o8, hh, ll);
    hv[j] = hh; lv[j] = ll;
  }
  *(short8*)&Hp[(size_t)wid * C + lane * 8] = hv;
  *(short8*)&Lp[(size_t)wid * C + lane * 8] = lv;
}

// ---------------- row sum of squares (codebook) ----------------------------
__global__ __launch_bounds__(256) void rowss_kernel(
    const float* __restrict__ src, float* __restrict__ dst, int nrows) {
  int wid  = (blockIdx.x * 256 + threadIdx.x) >> 6;
  int lane = threadIdx.x & 63;
  if (wid >= nrows) return;
  const float* s = src + (size_t)wid * C + lane * 8;
  float4 a  = *(const float4*)s;
  float4 b4 = *(const float4*)(s + 4);
  float sum = a.x*a.x + a.y*a.y + a.z*a.z + a.w*a.w
            + b4.x*b4.x + b4.y*b4.y + b4.z*b4.z + b4.w*b4.w;
#pragma unroll
  for (int o = 32; o >= 1; o >>= 1) sum += __shfl_xor(sum, o);
  if (lane == 0) dst[wid] = sum;
}

// ---------------- fp32 -> hi/lo split (whole tensor) -----------------------
__global__ __launch_bounds__(256) void split_kernel(
    const float* __restrict__ x, short* __restrict__ Hp, short* __restrict__ Lp) {
  size_t i = ((size_t)blockIdx.x * 256 + threadIdx.x) * 8;
  float4 a  = *(const float4*)&x[i];
  float4 b4 = *(const float4*)&x[i + 4];
  float v[8] = {a.x, a.y, a.z, a.w, b4.x, b4.y, b4.z, b4.w};
  short8 hv, lv;
#pragma unroll
  for (int j = 0; j < 8; j++) {
    short hh, ll;
    f2hsplit(v[j], hh, ll);
    hv[j] = hh; lv[j] = ll;
  }
  *(short8*)&Hp[i] = hv;
  *(short8*)&Lp[i] = lv;
}

// ---------------- weight transpose + split: W(K,N) -> H/L (N,K) ------------
__global__ __launch_bounds__(256) void wconvT_kernel(
    const float* __restrict__ W, short* __restrict__ Hp, short* __restrict__ Lp,
    int K, int N) {
  __shared__ float t[32][33];
  int tx = threadIdx.x, ty = threadIdx.y;
  int n0 = blockIdx.x * 32, k0 = blockIdx.y * 32;
#pragma unroll
  for (int r = 0; r < 4; r++) {
    int k = ty + r * 8;
    t[k][tx] = W[(size_t)(k0 + k) * N + n0 + tx];
  }
  __syncthreads();
#pragma unroll
  for (int r = 0; r < 4; r++) {
    int n = ty + r * 8;
    short h, l;
    f2hsplit(t[tx][n], h, l);
    Hp[(size_t)(n0 + n) * K + k0 + tx] = h;
    Lp[(size_t)(n0 + n) * K + k0 + tx] = l;
  }
}

// ---------------- codebook split (already N-major) -------------------------
__global__ __launch_bounds__(256) void wconv_kernel(
    const float* __restrict__ W, short* __restrict__ Hp, short* __restrict__ Lp) {
  size_t i = ((size_t)blockIdx.x * 256 + threadIdx.x) * 4;
  float4 a = *(const float4*)&W[i];
  float v[4] = {a.x, a.y, a.z, a.w};
  short hv[4], lv[4];
#pragma unroll
  for (int j = 0; j < 4; j++) f2hsplit(v[j], hv[j], lv[j]);
  *(short4*)&Hp[i] = *(short4*)hv;
  *(short4*)&Lp[i] = *(short4*)lv;
}

// ------- fp16-pair MFMA GEMM, 128x128 tile, BK=32, 8 waves (512 thr) -------
// A planes [M][K], B planes [N][K]; C = A * B^T (+ epilogue).
// LO=1: acc = accH(h*h) + 2^-11 * accL(h*lw + la*h). LO=0: h*h only.
// EPI: 0 = fp32 out+bias (qkv); 1 = gelu -> hi/lo planes (fc1);
//      2 = +bias+resid fp32 (proj/fc2); 3 = VQ top-2-per-tile packed keys
template <int EPI, int LO>
__global__ __launch_bounds__(512) void mgemm(
    const short* __restrict__ Ah, const short* __restrict__ Al,
    const short* __restrict__ Bh, const short* __restrict__ Bl,
    const int K, const float* __restrict__ bias,
    float* __restrict__ outF, short* __restrict__ outH, short* __restrict__ outL,
    const int ldo,
    const float* __restrict__ resid, const int rowOff, const int perm, const int shift,
    const float* __restrict__ c2, unsigned* __restrict__ pk) {
  constexpr int LDSZ = LO ? 16384 : 8192;
  __shared__ short lds[LDSZ];
  int m0, n0, ny;
  if constexpr (EPI == 3) {
    // m-slab XCD swizzle: XCD k owns m-tiles [32k,32k+32) x all n-tiles.
    int bid = blockIdx.y * gridDim.x + blockIdx.x;
    int xcd = bid & 7, idx = bid >> 3;
    m0 = (xcd * 32 + (idx & 31)) * 128;
    ny = idx >> 5;
    n0 = ny * 128;
  } else {
    m0 = blockIdx.x * 128; n0 = blockIdx.y * 128; ny = blockIdx.y;
  }
  const int t  = threadIdx.x;
  const int wv = t >> 6, ln = t & 63;
  const int wr = (wv >> 2) * 64, wc = (wv & 3) * 32;   // wave tile 64x32
  const int l15 = ln & 15, l4 = ln >> 4;

  f32x4 accH[4][2], accL[4][2];
#pragma unroll
  for (int mf = 0; mf < 4; mf++)
#pragma unroll
    for (int nf = 0; nf < 2; nf++) {
      accH[mf][nf] = (f32x4){0.f, 0.f, 0.f, 0.f};
      if constexpr (LO) accL[mf][nf] = (f32x4){0.f, 0.f, 0.f, 0.f};
    }

  const int srow = ln >> 2;                              // row within 16-row chunk
  const int scol = ((ln & 3) ^ ((ln >> 3) & 3)) * 8;     // pre-swizzled source chunk

  short* As_h = lds;
  short* Bs_h = lds + 4096;
  short* As_l = lds + (LO ? 8192 : 0);
  short* Bs_l = lds + (LO ? 12288 : 0);

  auto frag = [&](const short* lt, int rbase) -> f16x8 {
    int r = rbase + l15;
    int kc = l4 ^ ((r >> 1) & 3);
    return *(const f16x8*)(lt + (r >> 4) * 512 + (r & 15) * 32 + kc * 8);
  };

  for (int k0 = 0; k0 < K; k0 += 32) {
    size_t ra = (size_t)(m0 + wv * 16 + srow) * K + k0 + scol;
    size_t rb = (size_t)(n0 + wv * 16 + srow) * K + k0 + scol;
    gload16(Ah + ra, As_h + wv * 512);
    gload16(Bh + rb, Bs_h + wv * 512);
    if constexpr (LO) {
      gload16(Al + ra, As_l + wv * 512);
      gload16(Bl + rb, Bs_l + wv * 512);
    }
    __syncthreads();
    f16x8 ah[4], bh[2];
#pragma unroll
    for (int mf = 0; mf < 4; mf++) ah[mf] = frag(As_h, wr + mf * 16);
#pragma unroll
    for (int nf = 0; nf < 2; nf++) bh[nf] = frag(Bs_h, wc + nf * 16);
#pragma unroll
    for (int mf = 0; mf < 4; mf++)
#pragma unroll
      for (int nf = 0; nf < 2; nf++)
        accH[mf][nf] = __builtin_amdgcn_mfma_f32_16x16x32_f16(ah[mf], bh[nf], accH[mf][nf], 0, 0, 0);
    if constexpr (LO) {
      f16x8 bl[2];
#pragma unroll
      for (int nf = 0; nf < 2; nf++) bl[nf] = frag(Bs_l, wc + nf * 16);
#pragma unroll
      for (int mf = 0; mf < 4; mf++)
#pragma unroll
        for (int nf = 0; nf < 2; nf++)
          accL[mf][nf] = __builtin_amdgcn_mfma_f32_16x16x32_f16(ah[mf], bl[nf], accL[mf][nf], 0, 0, 0);
#pragma unroll
      for (int mf = 0; mf < 4; mf++) {
        f16x8 al = frag(As_l, wr + mf * 16);
#pragma unroll
        for (int nf = 0; nf < 2; nf++)
          accL[mf][nf] = __builtin_amdgcn_mfma_f32_16x16x32_f16(al, bh[nf], accL[mf][nf], 0, 0, 0);
      }
    }
    __syncthreads();
  }

  // combine hi/lo accumulators
  f32x4 acc[4][2];
#pragma unroll
  for (int mf = 0; mf < 4; mf++)
#pragma unroll
    for (int nf = 0; nf < 2; nf++) {
      if constexpr (LO) {
#pragma unroll
        for (int r = 0; r < 4; r++)
          acc[mf][nf][r] = fmaf(accL[mf][nf][r], LINV, accH[mf][nf][r]);
      } else {
        acc[mf][nf] = accH[mf][nf];
      }
    }

  if (EPI == 0) {
#pragma unroll
    for (int mf = 0; mf < 4; mf++)
#pragma unroll
      for (int r = 0; r < 4; r++) {
        int row = m0 + wr + mf * 16 + l4 * 4 + r;
        float* op = outF + (size_t)row * ldo;
#pragma unroll
        for (int nf = 0; nf < 2; nf++) {
          int col = n0 + wc + nf * 16 + l15;
          op[col] = acc[mf][nf][r] + bias[col];
        }
      }
  } else if (EPI == 1) {
#pragma unroll
    for (int mf = 0; mf < 4; mf++)
#pragma unroll
      for (int r = 0; r < 4; r++) {
        int row = m0 + wr + mf * 16 + l4 * 4 + r;
#pragma unroll
        for (int nf = 0; nf < 2; nf++) {
          int col = n0 + wc + nf * 16 + l15;
          float v = acc[mf][nf][r] + bias[col];
          v = 0.5f * v * (1.0f + erff(v * 0.70710678118654752f));
          short h, l;
          f2hsplit(v, h, l);
          outH[(size_t)row * ldo + col] = h;
          outL[(size_t)row * ldo + col] = l;
        }
      }
  } else if (EPI == 2) {
#pragma unroll
    for (int mf = 0; mf < 4; mf++)
#pragma unroll
      for (int r = 0; r < 4; r++) {
        int row = m0 + wr + mf * 16 + l4 * 4 + r;
        int orow = perm ? rowmap(row, shift) : (row + rowOff);
        const float* rp = resid + (size_t)orow * ldo;
        float* op = outF + (size_t)orow * ldo;
#pragma unroll
        for (int nf = 0; nf < 2; nf++) {
          int col = n0 + wc + nf * 16 + l15;
          op[col] = rp[col] + acc[mf][nf][r] + bias[col];
        }
      }
  } else {  // EPI == 3: top-2 per 128-col tile, packed keys
    unsigned* hk = (unsigned*)(void*)lds;   // [128 rows][4 quarters][2 entries]
#pragma unroll
    for (int mf = 0; mf < 4; mf++)
#pragma unroll
      for (int r = 0; r < 4; r++) {
        int wrow = wr + mf * 16 + l4 * 4 + r;
        unsigned k1 = 0xFFFFFFFFu, k2 = 0xFFFFFFFFu;
#pragma unroll
        for (int nf = 0; nf < 2; nf++) {
          int col = n0 + wc + nf * 16 + l15;
          float d = c2[col] - 2.0f * acc[mf][nf][r];
          unsigned kk = packkey(d, col);
          if (kk < k1) { k2 = k1; k1 = kk; }
          else if (kk < k2) { k2 = kk; }
        }
        // 16-lane (same l4) top-2 butterfly over the wave's 32 cols
#pragma unroll
        for (int o = 1; o <= 8; o <<= 1) {
          unsigned b1 = (unsigned)__shfl_xor((int)k1, o);
          unsigned b2 = (unsigned)__shfl_xor((int)k2, o);
          unsigned m1 = umn(k1, b1);
          unsigned m2 = umn(umx(k1, b1), umn(k2, b2));
          k1 = m1; k2 = m2;
        }
        if (l15 == 0) {
          hk[wrow * 8 + (wv & 3) * 2 + 0] = k1;
          hk[wrow * 8 + (wv & 3) * 2 + 1] = k2;
        }
      }
    __syncthreads();
    if (t < 128) {
      unsigned q1[4], q2[4];
#pragma unroll
      for (int i = 0; i < 4; i++) {
        q1[i] = hk[t * 8 + i * 2];
        q2[i] = hk[t * 8 + i * 2 + 1];
      }
      unsigned a1 = umn(q1[0], q1[1]);
      unsigned a2 = umn(umx(q1[0], q1[1]), umn(q2[0], q2[1]));
      unsigned b1 = umn(q1[2], q1[3]);
      unsigned b2 = umn(umx(q1[2], q1[3]), umn(q2[2], q2[3]));
      unsigned m1 = umn(a1, b1);
      unsigned m2 = umn(umx(a1, b1), umn(a2, b2));
      size_t base = (size_t)(m0 + t) * 64 + ny * 2;
      pk[base + 0] = m1;
      pk[base + 1] = m2;
    }
  }
}

// ---------------- candidate select + exact fp32 rescore + gather -----------
__global__ __launch_bounds__(256) void vq_out_kernel(
    const unsigned* __restrict__ pk, const float* __restrict__ x,
    const float* __restrict__ cb,
    float* __restrict__ outq, float* __restrict__ outidx) {
  int r = blockIdx.x * 4 + (threadIdx.x >> 6);
  int lane = threadIdx.x & 63;
  unsigned key = pk[(size_t)r * 64 + lane];
  unsigned kmin = key;
#pragma unroll
  for (int o = 32; o >= 1; o >>= 1) kmin = umn(kmin, (unsigned)__shfl_xor((int)kmin, o));
  float dmin = unpackd(kmin);
  unsigned long long mask = __ballot(unpackd(key) <= dmin + 2.0f);

  const float* xr = x + (size_t)r * C + lane * 8;
  float4 xa = *(const float4*)xr;
  float4 xb = *(const float4*)(xr + 4);

  float bestd = 3.4e38f;
  int   besti = 0x7fffffff;
  while (mask) {
    int l = __ffsll(mask) - 1;
    mask &= mask - 1;
    int col = ((unsigned)__shfl((int)key, l)) & 0xFFFu;
    const float* cr = cb + (size_t)col * C + lane * 8;
    float4 ca = *(const float4*)cr;
    float4 cb4 = *(const float4*)(cr + 4);
    float s = 0.f;
    s = fmaf(ca.x, ca.x - 2.f * xa.x, s);
    s = fmaf(ca.y, ca.y - 2.f * xa.y, s);
    s = fmaf(ca.z, ca.z - 2.f * xa.z, s);
    s = fmaf(ca.w, ca.w - 2.f * xa.w, s);
    s = fmaf(cb4.x, cb4.x - 2.f * xb.x, s);
    s = fmaf(cb4.y, cb4.y - 2.f * xb.y, s);
    s = fmaf(cb4.z, cb4.z - 2.f * xb.z, s);
    s = fmaf(cb4.w, cb4.w - 2.f * xb.w, s);
#pragma unroll
    for (int o = 32; o >= 1; o >>= 1) s += __shfl_xor(s, o);
    if (s < bestd || (s == bestd && col < besti)) { bestd = s; besti = col; }
  }
  const float4* src = (const float4*)(cb + (size_t)besti * C + lane * 8);
  float4*       dst = (float4*)(outq + (size_t)r * C + lane * 8);
  dst[0] = src[0];
  dst[1] = src[1];
  if (lane == 0) outidx[r] = (float)besti;
}

// ---------------- fused per-(window, head) attention (fp32) ----------------
__global__ __launch_bounds__(256) void attn_kernel(
    const float* __restrict__ qkv,   // chunk-local windowed rows x 1536
    const float* __restrict__ rpb,   // (225, 8)
    short* __restrict__ Hout, short* __restrict__ Lout,  // global windowed rows x 512
    int winOff, int shift) {
  int wl = blockIdx.x;
  int h  = blockIdx.y;
  int t  = threadIdx.x;
  __shared__ float q[64][64], k[64][64], v[64][64], pT[64][64];

  const float* base = qkv + (size_t)wl * 64 * 1536 + h * 64;
#pragma unroll
  for (int rep = 0; rep < 4; rep++) {
    int f = t + rep * 256;
    int i = f >> 4, dq = (f & 15) * 4;
    const float* rowp = base + (size_t)i * 1536 + dq;
    float4 qv = *(const float4*)(rowp);
    float4 kv = *(const float4*)(rowp + 512);
    float4 vv = *(const float4*)(rowp + 1024);
    q[i][dq] = qv.x * 0.125f; q[i][dq + 1] = qv.y * 0.125f;
    q[i][dq + 2] = qv.z * 0.125f; q[i][dq + 3] = qv.w * 0.125f;
    *(float4*)&k[i][dq] = kv;
    *(float4*)&v[i][dq] = vv;
  }
  __syncthreads();

  int i  = t >> 2;
  int jg = t & 3;
  int wim = (winOff + wl) & 15;
  int wy = wim >> 2, wx = wim & 3;
  int iy = i >> 3, ix = i & 7;

  float qreg[64];
#pragma unroll
  for (int d = 0; d < 64; d += 4) *(float4*)&qreg[d] = *(float4*)&q[i][d];

  int ci = 0;
  if (shift) ci = region(wy * 8 + iy) * 3 + region(wx * 8 + ix);

  float sc[16];
#pragma unroll
  for (int jj = 0; jj < 16; jj++) {
    int j = jg * 16 + jj;
    float s = 0.f;
#pragma unroll
    for (int d = 0; d < 64; d += 4) {
      float4 kv = *(float4*)&k[j][d];
      s = fmaf(qreg[d], kv.x, s);
      s = fmaf(qreg[d + 1], kv.y, s);
      s = fmaf(qreg[d + 2], kv.z, s);
      s = fmaf(qreg[d + 3], kv.w, s);
    }
    int jy = j >> 3, jx = j & 7;
    s += rpb[((iy - jy + 7) * 15 + (ix - jx + 7)) * 8 + h];
    if (shift) {
      int cj = region(wy * 8 + jy) * 3 + region(wx * 8 + jx);
      if (ci != cj) s -= 100.0f;
    }
    sc[jj] = s;
  }
  float mx = sc[0];
#pragma unroll
  for (int jj = 1; jj < 16; jj++) mx = fmaxf(mx, sc[jj]);
  mx = fmaxf(mx, __shfl_xor(mx, 1));
  mx = fmaxf(mx, __shfl_xor(mx, 2));
  float sum = 0.f;
#pragma unroll
  for (int jj = 0; jj < 16; jj++) { sc[jj] = expf(sc[jj] - mx); sum += sc[jj]; }
  sum += __shfl_xor(sum, 1);
  sum += __shfl_xor(sum, 2);
  float inv = 1.0f / sum;
#pragma unroll
  for (int jj = 0; jj < 16; jj++) pT[jg * 16 + jj][i] = sc[jj] * inv;
  __syncthreads();

  float accv[16];
#pragma unroll
  for (int dd = 0; dd < 16; dd++) accv[dd] = 0.f;
  for (int j = 0; j < 64; j++) {
    float pij = pT[j][i];
#pragma unroll
    for (int dd = 0; dd < 16; dd += 4) {
      float4 vv = *(float4*)&v[j][jg * 16 + dd];
      accv[dd]     = fmaf(pij, vv.x, accv[dd]);
      accv[dd + 1] = fmaf(pij, vv.y, accv[dd + 1]);
      accv[dd + 2] = fmaf(pij, vv.z, accv[dd + 2]);
      accv[dd + 3] = fmaf(pij, vv.w, accv[dd + 3]);
    }
  }
  size_t obase = ((size_t)(winOff + wl) * 64 + i) * 512 + h * 64 + jg * 16;
  short8 hv, lv;
#pragma unroll
  for (int half = 0; half < 2; half++) {
#pragma unroll
    for (int j = 0; j < 8; j++) {
      short hh, ll;
      f2hsplit(accv[half * 8 + j], hh, ll);
      hv[j] = hh; lv[j] = ll;
    }
    *(short8*)&Hout[obase + half * 8] = hv;
    *(short8*)&Lout[obase + half * 8] = lv;
  }
}

}  // namespace

extern "C" void kernel_launch(void* const* d_in, const int* in_sizes, int n_in,
                              void* d_out, int out_size, void* d_ws, size_t ws_size,
                              hipStream_t stream) {
  const float* x_in = (const float*)d_in[0];
  const float* n1g  = (const float*)d_in[1];
  const float* n1b  = (const float*)d_in[2];
  const float* qkvw = (const float*)d_in[3];
  const float* qkvb = (const float*)d_in[4];
  const float* rpb  = (const float*)d_in[5];
  const float* pw   = (const float*)d_in[6];
  const float* pb   = (const float*)d_in[7];
  const float* n2g  = (const float*)d_in[8];
  const float* n2b  = (const float*)d_in[9];
  const float* f1w  = (const float*)d_in[10];
  const float* f1b  = (const float*)d_in[11];
  const float* f2w  = (const float*)d_in[12];
  const float* f2b_ = (const float*)d_in[13];
  const float* cb   = (const float*)d_in[14];

  float* outq   = (float*)d_out;
  float* outidx = outq + 16777216;
  short* Hbuf = (short*)d_out;                 // hi plane: first 32MB of outq
  short* Lbuf = Hbuf + (size_t)ROWS * 512;     // lo plane: second 32MB

  char* ws = (char*)d_ws;
  float* Abuf = (float*)ws;                               // 64MiB residual stream
  short* Wb   = (short*)(ws + ((size_t)64 << 20));        // 32MiB weight planes
  char*  Cbuf = ws + ((size_t)96 << 20);                  // chunk scratch
  const int Rrows = (ws_size >= ((size_t)130 << 20)) ? 4096 : 2048;

  const int SZ_QKV = 512 * 1536, SZ_P = 512 * 512, SZ_F1 = 512 * 2048, SZ_F2 = 2048 * 512;
  const int PB = (SZ_QKV + SZ_P + SZ_F1 + SZ_F2) * 2;
  short* cbH = Wb + (size_t)2 * PB;
  short* cbL = cbH + 4096 * 512;

  // ---- one-time (per launch) weight transpose + split ----
  for (int blk = 0; blk < 2; blk++) {
    short* base = Wb + (size_t)blk * PB;
    short* qH = base;          short* qL = qH + SZ_QKV;
    short* pH = qL + SZ_QKV;   short* pL = pH + SZ_P;
    short* f1H = pL + SZ_P;    short* f1L = f1H + SZ_F1;
    short* f2H = f1L + SZ_F1;  short* f2L = f2H + SZ_F2;
    wconvT_kernel<<<dim3(48, 16), dim3(32, 8), 0, stream>>>(qkvw + (size_t)blk * SZ_QKV, qH, qL, 512, 1536);
    wconvT_kernel<<<dim3(16, 16), dim3(32, 8), 0, stream>>>(pw + (size_t)blk * SZ_P, pH, pL, 512, 512);
    wconvT_kernel<<<dim3(64, 16), dim3(32, 8), 0, stream>>>(f1w + (size_t)blk * SZ_F1, f1H, f1L, 512, 2048);
    wconvT_kernel<<<dim3(16, 64), dim3(32, 8), 0, stream>>>(f2w + (size_t)blk * SZ_F2, f2H, f2L, 2048, 512);
  }
  wconv_kernel<<<2048, 256, 0, stream>>>(cb, cbH, cbL);

  const int nch = ROWS / Rrows;
  for (int blk = 0; blk < 2; blk++) {
    short* base = Wb + (size_t)blk * PB;
    short* qH = base;          short* qL = qH + SZ_QKV;
    short* pH = qL + SZ_QKV;   short* pL = pH + SZ_P;
    short* f1H = pL + SZ_P;    short* f1L = f1H + SZ_F1;
    short* f2H = f1L + SZ_F1;  short* f2L = f2H + SZ_F2;
    const float* xcur = blk ? (const float*)Abuf : x_in;
    int shift = blk ? 4 : 0;

    // LN1 + shift + window partition -> hi/lo planes (windowed order)
    ln_split_kernel<<<8192, 256, 0, stream>>>(xcur, Hbuf, Lbuf, n1g + blk * 512, n1b + blk * 512, shift, 1);

    // qkv GEMM (fp32 out) + attention (writes planes back in place)
    float* Cq = (float*)Cbuf;
    for (int ch = 0; ch < nch; ch++) {
      int r0 = ch * Rrows;
      mgemm<0, 1><<<dim3(Rrows / 128, 12), 512, 0, stream>>>(
          Hbuf + (size_t)r0 * 512, Lbuf + (size_t)r0 * 512, qH, qL, 512,
          qkvb + blk * 1536, Cq, nullptr, nullptr, 1536,
          nullptr, 0, 0, 0, nullptr, nullptr);
      attn_kernel<<<dim3(Rrows / 64, 8), 256, 0, stream>>>(
          Cq, rpb + blk * 1800, Hbuf, Lbuf, r0 >> 6, shift);
    }

    // proj + window reverse + unshift + residual -> Abuf (fp32)
    mgemm<2, 1><<<dim3(256, 4), 512, 0, stream>>>(
        Hbuf, Lbuf, pH, pL, 512, pb + blk * 512,
        Abuf, nullptr, nullptr, 512,
        blk ? (const float*)Abuf : x_in, 0, 1, shift, nullptr, nullptr);

    // LN2 -> planes (identity order)
    ln_split_kernel<<<8192, 256, 0, stream>>>(Abuf, Hbuf, Lbuf, n2g + blk * 512, n2b + blk * 512, 0, 0);

    // MLP
    short* gh = (short*)Cbuf;
    short* gl = gh + (size_t)Rrows * 2048;
    for (int ch = 0; ch < nch; ch++) {
      int r0 = ch * Rrows;
      mgemm<1, 1><<<dim3(Rrows / 128, 16), 512, 0, stream>>>(
          Hbuf + (size_t)r0 * 512, Lbuf + (size_t)r0 * 512, f1H, f1L, 512,
          f1b + blk * 2048, nullptr, gh, gl, 2048,
          nullptr, 0, 0, 0, nullptr, nullptr);
      mgemm<2, 1><<<dim3(Rrows / 128, 4), 512, 0, stream>>>(
          gh, gl, f2H, f2L, 2048, f2b_ + blk * 512,
          Abuf, nullptr, nullptr, 512,
          Abuf, r0, 0, 0, nullptr, nullptr);
    }
  }

  // ---- VQ: approx top-2/tile via single-pass fp16 GEMM, exact rescore ----
  split_kernel<<<8192, 256, 0, stream>>>(Abuf, Hbuf, Lbuf);
  float*    c2  = (float*)Cbuf;                              // 16 KB
  unsigned* pkb = (unsigned*)(Cbuf + ((size_t)64 << 10));    // 8 MiB: 32768 x 64 keys
  rowss_kernel<<<1024, 256, 0, stream>>>(cb, c2, 4096);
  mgemm<3, 0><<<dim3(256, 32), 512, 0, stream>>>(
      Hbuf, Lbuf, cbH, cbL, 512, nullptr,
      nullptr, nullptr, nullptr, 0,
      nullptr, 0, 0, 0, c2, pkb);
  vq_out_kernel<<<8192, 256, 0, stream>>>(pkb, Abuf, cb, outq, outidx);
}

// Round 8
// 2423.854 us; speedup vs baseline: 3.5706x; 1.3302x over previous
//
#include <hip/hip_runtime.h>
#include <math.h>

#define DEV __device__ __forceinline__

typedef __attribute__((ext_vector_type(8))) _Float16 f16x8;
typedef __attribute__((ext_vector_type(8))) short short8;
typedef __attribute__((ext_vector_type(4))) float f32x4;

namespace {

constexpr int C = 512;
constexpr int ROWS = 32768;   // B * L
constexpr float LSCALE = 2048.0f;        // lo-plane pre-scale (2^11)
constexpr float LINV   = 1.0f / 2048.0f;
constexpr float F16MIN = 6.1035156e-5f;  // fp16 min normal

// fp32 -> fp16 hi/lo split. h = RTN(x) (flushed to 0 below normal range),
// l = RTN((x - h) * 2^11). Ensures all MFMA inputs are 0 or normal fp16.
DEV void f2hsplit(float x, short& hs, short& ls) {
  _Float16 h = (_Float16)x;
  float hf = (float)h;
  if (fabsf(hf) < F16MIN) { h = (_Float16)0.0f; hf = 0.f; }
  _Float16 l = (_Float16)((x - hf) * LSCALE);
  if (fabsf((float)l) < F16MIN) l = (_Float16)0.0f;
  hs = __builtin_bit_cast(short, h);
  ls = __builtin_bit_cast(short, l);
}

DEV unsigned umn(unsigned a, unsigned b) { return a < b ? a : b; }
DEV unsigned umx(unsigned a, unsigned b) { return a > b ? a : b; }

// monotone key: high 20 bits = sign-flipped fp32 distance, low 12 = col idx.
DEV unsigned packkey(float d, int col) {
  unsigned u = __builtin_bit_cast(unsigned, d);
  u = (u & 0x80000000u) ? ~u : (u | 0x80000000u);
  return (u & 0xFFFFF000u) | (unsigned)col;
}
DEV float unpackd(unsigned k) {
  unsigned u = (k & 0x80000000u) ? (k ^ 0x80000000u) : ~k;
  return __builtin_bit_cast(float, u);
}

// windowed row r -> flat row in (b, y, x) order, for roll by `shift`.
DEV int rowmap(int r, int shift) {
  int b  = r >> 10;
  int w  = (r >> 6) & 15;
  int wy = w >> 2, wx = w & 3;
  int ii = r & 63;
  int iy = ii >> 3, ix = ii & 7;
  int y = (wy * 8 + iy + shift) & 31;
  int x = (wx * 8 + ix + shift) & 31;
  return (b << 10) + (y << 5) + x;
}

DEV int region(int y) { return (y < 24) ? 0 : ((y < 28) ? 1 : 2); }

typedef __attribute__((address_space(1))) const unsigned int gu32;
typedef __attribute__((address_space(3))) unsigned int lu32;
DEV void gload16(const void* g, void* l) {
  __builtin_amdgcn_global_load_lds((gu32*)g, (lu32*)l, 16, 0, 0);
}

// ---------------- LayerNorm -> fp16 hi/lo planes ---------------------------
__global__ __launch_bounds__(256) void ln_split_kernel(
    const float* __restrict__ src, short* __restrict__ Hp, short* __restrict__ Lp,
    const float* __restrict__ g, const float* __restrict__ b,
    int shift, int windowed) {
  int wid  = (blockIdx.x * 256 + threadIdx.x) >> 6;
  int lane = threadIdx.x & 63;
  if (wid >= ROWS) return;
  int srcRow = windowed ? rowmap(wid, shift) : wid;
  const float* s = src + (size_t)srcRow * C + lane * 8;
  float v[8];
  *(float4*)(v)     = *(const float4*)(s);
  *(float4*)(v + 4) = *(const float4*)(s + 4);
  float sum = 0.f;
#pragma unroll
  for (int j = 0; j < 8; j++) sum += v[j];
#pragma unroll
  for (int o = 32; o >= 1; o >>= 1) sum += __shfl_xor(sum, o);
  float mu = sum * (1.0f / 512.0f);
  float vs = 0.f;
#pragma unroll
  for (int j = 0; j < 8; j++) { float d = v[j] - mu; vs += d * d; }
#pragma unroll
  for (int o = 32; o >= 1; o >>= 1) vs += __shfl_xor(vs, o);
  float rs = rsqrtf(vs * (1.0f / 512.0f) + 1e-5f);
  float gg[8], bb[8];
  *(float4*)gg       = *(const float4*)&g[lane * 8];
  *(float4*)(gg + 4) = *(const float4*)&g[lane * 8 + 4];
  *(float4*)bb       = *(const float4*)&b[lane * 8];
  *(float4*)(bb + 4) = *(const float4*)&b[lane * 8 + 4];
  short8 hv, lv;
#pragma unroll
  for (int j = 0; j < 8; j++) {
    float o8 = (v[j] - mu) * rs * gg[j] + bb[j];
    short hh, ll;
    f2hsplit(o8, hh, ll);
    hv[j] = hh; lv[j] = ll;
  }
  *(short8*)&Hp[(size_t)wid * C + lane * 8] = hv;
  *(short8*)&Lp[(size_t)wid * C + lane * 8] = lv;
}

// ---------------- row sum of squares (codebook) ----------------------------
__global__ __launch_bounds__(256) void rowss_kernel(
    const float* __restrict__ src, float* __restrict__ dst, int nrows) {
  int wid  = (blockIdx.x * 256 + threadIdx.x) >> 6;
  int lane = threadIdx.x & 63;
  if (wid >= nrows) return;
  const float* s = src + (size_t)wid * C + lane * 8;
  float4 a  = *(const float4*)s;
  float4 b4 = *(const float4*)(s + 4);
  float sum = a.x*a.x + a.y*a.y + a.z*a.z + a.w*a.w
            + b4.x*b4.x + b4.y*b4.y + b4.z*b4.z + b4.w*b4.w;
#pragma unroll
  for (int o = 32; o >= 1; o >>= 1) sum += __shfl_xor(sum, o);
  if (lane == 0) dst[wid] = sum;
}

// ---------------- weight transpose + split: W(K,N) -> H/L (N,K) ------------
__global__ __launch_bounds__(256) void wconvT_kernel(
    const float* __restrict__ W, short* __restrict__ Hp, short* __restrict__ Lp,
    int K, int N) {
  __shared__ float t[32][33];
  int tx = threadIdx.x, ty = threadIdx.y;
  int n0 = blockIdx.x * 32, k0 = blockIdx.y * 32;
#pragma unroll
  for (int r = 0; r < 4; r++) {
    int k = ty + r * 8;
    t[k][tx] = W[(size_t)(k0 + k) * N + n0 + tx];
  }
  __syncthreads();
#pragma unroll
  for (int r = 0; r < 4; r++) {
    int n = ty + r * 8;
    short h, l;
    f2hsplit(t[tx][n], h, l);
    Hp[(size_t)(n0 + n) * K + k0 + tx] = h;
    Lp[(size_t)(n0 + n) * K + k0 + tx] = l;
  }
}

// ---------------- codebook split (already N-major) -------------------------
__global__ __launch_bounds__(256) void wconv_kernel(
    const float* __restrict__ W, short* __restrict__ Hp, short* __restrict__ Lp) {
  size_t i = ((size_t)blockIdx.x * 256 + threadIdx.x) * 4;
  float4 a = *(const float4*)&W[i];
  float v[4] = {a.x, a.y, a.z, a.w};
  short hv[4], lv[4];
#pragma unroll
  for (int j = 0; j < 4; j++) f2hsplit(v[j], hv[j], lv[j]);
  *(short4*)&Hp[i] = *(short4*)hv;
  *(short4*)&Lp[i] = *(short4*)lv;
}

// ------- fp16-pair MFMA GEMM, 128x128 tile, BK=32, 8 waves (512 thr) -------
// A planes [M][K], B planes [N][K]; C = A * B^T (+ epilogue).
// acc = accH(h*h) + 2^-11 * accL(h*lw + la*h); la/lw are pre-scaled by 2^11.
// EPI: 0 = fp32 out+bias (qkv); 1 = gelu -> hi/lo planes (fc1);
//      2 = +bias+resid fp32 (proj/fc2); 4 = EPI2 + h/l plane store
template <int EPI>
__global__ __launch_bounds__(512) void mgemm(
    const short* __restrict__ Ah, const short* __restrict__ Al,
    const short* __restrict__ Bh, const short* __restrict__ Bl,
    const int K, const float* __restrict__ bias,
    float* __restrict__ outF, short* __restrict__ outH, short* __restrict__ outL,
    const int ldo,
    const float* __restrict__ resid, const int rowOff, const int perm, const int shift) {
  __shared__ short lds[16384];
  const int m0 = blockIdx.x * 128, n0 = blockIdx.y * 128;
  const int t  = threadIdx.x;
  const int wv = t >> 6, ln = t & 63;
  const int wr = (wv >> 2) * 64, wc = (wv & 3) * 32;   // wave tile 64x32
  const int l15 = ln & 15, l4 = ln >> 4;

  f32x4 accH[4][2], accL[4][2];
#pragma unroll
  for (int mf = 0; mf < 4; mf++)
#pragma unroll
    for (int nf = 0; nf < 2; nf++) {
      accH[mf][nf] = (f32x4){0.f, 0.f, 0.f, 0.f};
      accL[mf][nf] = (f32x4){0.f, 0.f, 0.f, 0.f};
    }

  const int srow = ln >> 2;                              // row within 16-row chunk
  const int scol = ((ln & 3) ^ ((ln >> 3) & 3)) * 8;     // pre-swizzled source chunk

  short* As_h = lds;
  short* Bs_h = lds + 4096;
  short* As_l = lds + 8192;
  short* Bs_l = lds + 12288;

  auto frag = [&](const short* lt, int rbase) -> f16x8 {
    int r = rbase + l15;
    int kc = l4 ^ ((r >> 1) & 3);
    return *(const f16x8*)(lt + (r >> 4) * 512 + (r & 15) * 32 + kc * 8);
  };

  for (int k0 = 0; k0 < K; k0 += 32) {
    size_t ra = (size_t)(m0 + wv * 16 + srow) * K + k0 + scol;
    size_t rb = (size_t)(n0 + wv * 16 + srow) * K + k0 + scol;
    gload16(Ah + ra, As_h + wv * 512);
    gload16(Bh + rb, Bs_h + wv * 512);
    gload16(Al + ra, As_l + wv * 512);
    gload16(Bl + rb, Bs_l + wv * 512);
    __syncthreads();
    f16x8 ah[4], bh[2], bl[2];
#pragma unroll
    for (int mf = 0; mf < 4; mf++) ah[mf] = frag(As_h, wr + mf * 16);
#pragma unroll
    for (int nf = 0; nf < 2; nf++) bh[nf] = frag(Bs_h, wc + nf * 16);
#pragma unroll
    for (int mf = 0; mf < 4; mf++)
#pragma unroll
      for (int nf = 0; nf < 2; nf++)
        accH[mf][nf] = __builtin_amdgcn_mfma_f32_16x16x32_f16(ah[mf], bh[nf], accH[mf][nf], 0, 0, 0);
#pragma unroll
    for (int nf = 0; nf < 2; nf++) bl[nf] = frag(Bs_l, wc + nf * 16);
#pragma unroll
    for (int mf = 0; mf < 4; mf++)
#pragma unroll
      for (int nf = 0; nf < 2; nf++)
        accL[mf][nf] = __builtin_amdgcn_mfma_f32_16x16x32_f16(ah[mf], bl[nf], accL[mf][nf], 0, 0, 0);
#pragma unroll
    for (int mf = 0; mf < 4; mf++) {
      f16x8 al = frag(As_l, wr + mf * 16);
#pragma unroll
      for (int nf = 0; nf < 2; nf++)
        accL[mf][nf] = __builtin_amdgcn_mfma_f32_16x16x32_f16(al, bh[nf], accL[mf][nf], 0, 0, 0);
    }
    __syncthreads();
  }

  f32x4 acc[4][2];
#pragma unroll
  for (int mf = 0; mf < 4; mf++)
#pragma unroll
    for (int nf = 0; nf < 2; nf++)
#pragma unroll
      for (int r = 0; r < 4; r++)
        acc[mf][nf][r] = fmaf(accL[mf][nf][r], LINV, accH[mf][nf][r]);

  if (EPI == 0) {
#pragma unroll
    for (int mf = 0; mf < 4; mf++)
#pragma unroll
      for (int r = 0; r < 4; r++) {
        int row = m0 + wr + mf * 16 + l4 * 4 + r;
        float* op = outF + (size_t)row * ldo;
#pragma unroll
        for (int nf = 0; nf < 2; nf++) {
          int col = n0 + wc + nf * 16 + l15;
          op[col] = acc[mf][nf][r] + bias[col];
        }
      }
  } else if (EPI == 1) {
#pragma unroll
    for (int mf = 0; mf < 4; mf++)
#pragma unroll
      for (int r = 0; r < 4; r++) {
        int row = m0 + wr + mf * 16 + l4 * 4 + r;
#pragma unroll
        for (int nf = 0; nf < 2; nf++) {
          int col = n0 + wc + nf * 16 + l15;
          float v = acc[mf][nf][r] + bias[col];
          v = 0.5f * v * (1.0f + erff(v * 0.70710678118654752f));
          short h, l;
          f2hsplit(v, h, l);
          outH[(size_t)row * ldo + col] = h;
          outL[(size_t)row * ldo + col] = l;
        }
      }
  } else {  // EPI == 2 or 4
#pragma unroll
    for (int mf = 0; mf < 4; mf++)
#pragma unroll
      for (int r = 0; r < 4; r++) {
        int row = m0 + wr + mf * 16 + l4 * 4 + r;
        int orow = perm ? rowmap(row, shift) : (row + rowOff);
        const float* rp = resid + (size_t)orow * ldo;
        float* op = outF + (size_t)orow * ldo;
#pragma unroll
        for (int nf = 0; nf < 2; nf++) {
          int col = n0 + wc + nf * 16 + l15;
          float v = rp[col] + acc[mf][nf][r] + bias[col];
          op[col] = v;
          if (EPI == 4) {
            short h, l;
            f2hsplit(v, h, l);
            outH[(size_t)orow * ldo + col] = h;
            outL[(size_t)orow * ldo + col] = l;
          }
        }
      }
  }
}

// ------ VQ distance GEMM: h*h only, 128x128 tile, BK=64, 4 waves -----------
// top-2 per 128-col tile emitted as packed keys; exact rescore downstream.
__global__ __launch_bounds__(256) void vqgemm(
    const short* __restrict__ Ah, const short* __restrict__ Bh,
    const float* __restrict__ c2, unsigned* __restrict__ pk) {
  __shared__ short lds[16384];   // A 128x64 | B 128x64 fp16
  const int bid = blockIdx.x;
  const int xcd = bid & 7, idx = bid >> 3;
  const int m0 = (xcd * 32 + (idx & 31)) * 128;   // m-slab per XCD
  const int ny = idx >> 5;
  const int n0 = ny * 128;
  const int K = 512;
  const int t  = threadIdx.x;
  const int wv = t >> 6, ln = t & 63;
  const int wr = (wv >> 1) * 64, wc = (wv & 1) * 64;  // wave tile 64x64
  const int l15 = ln & 15, l4 = ln >> 4;

  f32x4 acc[4][4];
#pragma unroll
  for (int mf = 0; mf < 4; mf++)
#pragma unroll
    for (int nf = 0; nf < 4; nf++) acc[mf][nf] = (f32x4){0.f, 0.f, 0.f, 0.f};

  const int srow = ln >> 2;
  const int scol = ((ln & 3) ^ ((ln >> 3) & 3)) * 8;

  short* As = lds;            // 16 chunks: c = rowchunk + 8*khalf
  short* Bs = lds + 8192;

  auto frag = [&](const short* lt, int rbase) -> f16x8 {
    int r = rbase + l15;
    int kc = l4 ^ ((r >> 1) & 3);
    return *(const f16x8*)(lt + (r >> 4) * 512 + (r & 15) * 32 + kc * 8);
  };

  for (int k0 = 0; k0 < K; k0 += 64) {
#pragma unroll
    for (int q = 0; q < 8; q++) {
      int s = wv * 8 + q;                  // 0..31: 16 A chunks then 16 B
      int c = s & 15;
      int base0 = (s < 16) ? m0 : n0;
      const short* src = (s < 16) ? Ah : Bh;
      short* dst = ((s < 16) ? As : Bs) + c * 512;
      size_t ga = (size_t)(base0 + (c & 7) * 16 + srow) * K + k0 + (c >> 3) * 32 + scol;
      gload16(src + ga, dst);
    }
    __syncthreads();
#pragma unroll
    for (int kh = 0; kh < 2; kh++) {
      const short* Ab = As + kh * 4096;
      const short* Bb = Bs + kh * 4096;
      f16x8 ah[4], bh[4];
#pragma unroll
      for (int mf = 0; mf < 4; mf++) ah[mf] = frag(Ab, wr + mf * 16);
#pragma unroll
      for (int nf = 0; nf < 4; nf++) bh[nf] = frag(Bb, wc + nf * 16);
#pragma unroll
      for (int mf = 0; mf < 4; mf++)
#pragma unroll
        for (int nf = 0; nf < 4; nf++)
          acc[mf][nf] = __builtin_amdgcn_mfma_f32_16x16x32_f16(ah[mf], bh[nf], acc[mf][nf], 0, 0, 0);
    }
    __syncthreads();
  }

  // top-2 per row over this 128-col tile
  unsigned* hk = (unsigned*)(void*)lds;   // [128 rows][2 halves][2 entries]
#pragma unroll
  for (int mf = 0; mf < 4; mf++)
#pragma unroll
    for (int r = 0; r < 4; r++) {
      int wrow = wr + mf * 16 + l4 * 4 + r;
      unsigned k1 = 0xFFFFFFFFu, k2 = 0xFFFFFFFFu;
#pragma unroll
      for (int nf = 0; nf < 4; nf++) {
        int col = n0 + wc + nf * 16 + l15;
        float d = c2[col] - 2.0f * acc[mf][nf][r];
        unsigned kk = packkey(d, col);
        if (kk < k1) { k2 = k1; k1 = kk; }
        else if (kk < k2) { k2 = kk; }
      }
#pragma unroll
      for (int o = 1; o <= 8; o <<= 1) {
        unsigned b1 = (unsigned)__shfl_xor((int)k1, o);
        unsigned b2 = (unsigned)__shfl_xor((int)k2, o);
        unsigned m1 = umn(k1, b1);
        unsigned m2 = umn(umx(k1, b1), umn(k2, b2));
        k1 = m1; k2 = m2;
      }
      if (l15 == 0) {
        hk[wrow * 4 + (wv & 1) * 2 + 0] = k1;
        hk[wrow * 4 + (wv & 1) * 2 + 1] = k2;
      }
    }
  __syncthreads();
  if (t < 128) {
    unsigned a1 = hk[t * 4 + 0], a2 = hk[t * 4 + 1];
    unsigned b1 = hk[t * 4 + 2], b2 = hk[t * 4 + 3];
    unsigned m1 = umn(a1, b1);
    unsigned m2 = umn(umx(a1, b1), umn(a2, b2));
    size_t base = (size_t)(m0 + t) * 64 + ny * 2;
    pk[base + 0] = m1;
    pk[base + 1] = m2;
  }
}

// ---------------- candidate select + exact fp32 rescore + gather -----------
__global__ __launch_bounds__(256) void vq_out_kernel(
    const unsigned* __restrict__ pk, const float* __restrict__ x,
    const float* __restrict__ cb,
    float* __restrict__ outq, float* __restrict__ outidx) {
  int r = blockIdx.x * 4 + (threadIdx.x >> 6);
  int lane = threadIdx.x & 63;
  unsigned key = pk[(size_t)r * 64 + lane];
  unsigned kmin = key;
#pragma unroll
  for (int o = 32; o >= 1; o >>= 1) kmin = umn(kmin, (unsigned)__shfl_xor((int)kmin, o));
  float dmin = unpackd(kmin);
  unsigned long long mask = __ballot(unpackd(key) <= dmin + 2.0f);

  const float* xr = x + (size_t)r * C + lane * 8;
  float4 xa = *(const float4*)xr;
  float4 xb = *(const float4*)(xr + 4);

  float bestd = 3.4e38f;
  int   besti = 0x7fffffff;
  while (mask) {
    int l = __ffsll(mask) - 1;
    mask &= mask - 1;
    int col = ((unsigned)__shfl((int)key, l)) & 0xFFFu;
    const float* cr = cb + (size_t)col * C + lane * 8;
    float4 ca = *(const float4*)cr;
    float4 cb4 = *(const float4*)(cr + 4);
    float s = 0.f;
    s = fmaf(ca.x, ca.x - 2.f * xa.x, s);
    s = fmaf(ca.y, ca.y - 2.f * xa.y, s);
    s = fmaf(ca.z, ca.z - 2.f * xa.z, s);
    s = fmaf(ca.w, ca.w - 2.f * xa.w, s);
    s = fmaf(cb4.x, cb4.x - 2.f * xb.x, s);
    s = fmaf(cb4.y, cb4.y - 2.f * xb.y, s);
    s = fmaf(cb4.z, cb4.z - 2.f * xb.z, s);
    s = fmaf(cb4.w, cb4.w - 2.f * xb.w, s);
#pragma unroll
    for (int o = 32; o >= 1; o >>= 1) s += __shfl_xor(s, o);
    if (s < bestd || (s == bestd && col < besti)) { bestd = s; besti = col; }
  }
  const float4* src = (const float4*)(cb + (size_t)besti * C + lane * 8);
  float4*       dst = (float4*)(outq + (size_t)r * C + lane * 8);
  dst[0] = src[0];
  dst[1] = src[1];
  if (lane == 0) outidx[r] = (float)besti;
}

// ---------------- fused per-(window, head) attention (fp32) ----------------
__global__ __launch_bounds__(256) void attn_kernel(
    const float* __restrict__ qkv,   // chunk-local windowed rows x 1536
    const float* __restrict__ rpb,   // (225, 8)
    short* __restrict__ Hout, short* __restrict__ Lout,  // global windowed rows x 512
    int winOff, int shift) {
  int wl = blockIdx.x;
  int h  = blockIdx.y;
  int t  = threadIdx.x;
  __shared__ float q[64][64], k[64][64], v[64][64], pT[64][64];

  const float* base = qkv + (size_t)wl * 64 * 1536 + h * 64;
#pragma unroll
  for (int rep = 0; rep < 4; rep++) {
    int f = t + rep * 256;
    int i = f >> 4, dq = (f & 15) * 4;
    const float* rowp = base + (size_t)i * 1536 + dq;
    float4 qv = *(const float4*)(rowp);
    float4 kv = *(const float4*)(rowp + 512);
    float4 vv = *(const float4*)(rowp + 1024);
    q[i][dq] = qv.x * 0.125f; q[i][dq + 1] = qv.y * 0.125f;
    q[i][dq + 2] = qv.z * 0.125f; q[i][dq + 3] = qv.w * 0.125f;
    *(float4*)&k[i][dq] = kv;
    *(float4*)&v[i][dq] = vv;
  }
  __syncthreads();

  int i  = t >> 2;
  int jg = t & 3;
  int wim = (winOff + wl) & 15;
  int wy = wim >> 2, wx = wim & 3;
  int iy = i >> 3, ix = i & 7;

  float qreg[64];
#pragma unroll
  for (int d = 0; d < 64; d += 4) *(float4*)&qreg[d] = *(float4*)&q[i][d];

  int ci = 0;
  if (shift) ci = region(wy * 8 + iy) * 3 + region(wx * 8 + ix);

  float sc[16];
#pragma unroll
  for (int jj = 0; jj < 16; jj++) {
    int j = jg * 16 + jj;
    float s = 0.f;
#pragma unroll
    for (int d = 0; d < 64; d += 4) {
      float4 kv = *(float4*)&k[j][d];
      s = fmaf(qreg[d], kv.x, s);
      s = fmaf(qreg[d + 1], kv.y, s);
      s = fmaf(qreg[d + 2], kv.z, s);
      s = fmaf(qreg[d + 3], kv.w, s);
    }
    int jy = j >> 3, jx = j & 7;
    s += rpb[((iy - jy + 7) * 15 + (ix - jx + 7)) * 8 + h];
    if (shift) {
      int cj = region(wy * 8 + jy) * 3 + region(wx * 8 + jx);
      if (ci != cj) s -= 100.0f;
    }
    sc[jj] = s;
  }
  float mx = sc[0];
#pragma unroll
  for (int jj = 1; jj < 16; jj++) mx = fmaxf(mx, sc[jj]);
  mx = fmaxf(mx, __shfl_xor(mx, 1));
  mx = fmaxf(mx, __shfl_xor(mx, 2));
  float sum = 0.f;
#pragma unroll
  for (int jj = 0; jj < 16; jj++) { sc[jj] = expf(sc[jj] - mx); sum += sc[jj]; }
  sum += __shfl_xor(sum, 1);
  sum += __shfl_xor(sum, 2);
  float inv = 1.0f / sum;
#pragma unroll
  for (int jj = 0; jj < 16; jj++) pT[jg * 16 + jj][i] = sc[jj] * inv;
  __syncthreads();

  float accv[16];
#pragma unroll
  for (int dd = 0; dd < 16; dd++) accv[dd] = 0.f;
  for (int j = 0; j < 64; j++) {
    float pij = pT[j][i];
#pragma unroll
    for (int dd = 0; dd < 16; dd += 4) {
      float4 vv = *(float4*)&v[j][jg * 16 + dd];
      accv[dd]     = fmaf(pij, vv.x, accv[dd]);
      accv[dd + 1] = fmaf(pij, vv.y, accv[dd + 1]);
      accv[dd + 2] = fmaf(pij, vv.z, accv[dd + 2]);
      accv[dd + 3] = fmaf(pij, vv.w, accv[dd + 3]);
    }
  }
  size_t obase = ((size_t)(winOff + wl) * 64 + i) * 512 + h * 64 + jg * 16;
  short8 hv, lv;
#pragma unroll
  for (int half = 0; half < 2; half++) {
#pragma unroll
    for (int j = 0; j < 8; j++) {
      short hh, ll;
      f2hsplit(accv[half * 8 + j], hh, ll);
      hv[j] = hh; lv[j] = ll;
    }
    *(short8*)&Hout[obase + half * 8] = hv;
    *(short8*)&Lout[obase + half * 8] = lv;
  }
}

}  // namespace

extern "C" void kernel_launch(void* const* d_in, const int* in_sizes, int n_in,
                              void* d_out, int out_size, void* d_ws, size_t ws_size,
                              hipStream_t stream) {
  const float* x_in = (const float*)d_in[0];
  const float* n1g  = (const float*)d_in[1];
  const float* n1b  = (const float*)d_in[2];
  const float* qkvw = (const float*)d_in[3];
  const float* qkvb = (const float*)d_in[4];
  const float* rpb  = (const float*)d_in[5];
  const float* pw   = (const float*)d_in[6];
  const float* pb   = (const float*)d_in[7];
  const float* n2g  = (const float*)d_in[8];
  const float* n2b  = (const float*)d_in[9];
  const float* f1w  = (const float*)d_in[10];
  const float* f1b  = (const float*)d_in[11];
  const float* f2w  = (const float*)d_in[12];
  const float* f2b_ = (const float*)d_in[13];
  const float* cb   = (const float*)d_in[14];

  float* outq   = (float*)d_out;
  float* outidx = outq + 16777216;
  short* Hbuf = (short*)d_out;                 // hi plane: first 32MB of outq
  short* Lbuf = Hbuf + (size_t)ROWS * 512;     // lo plane: second 32MB

  char* ws = (char*)d_ws;
  float* Abuf = (float*)ws;                               // 64MiB residual stream
  short* Wb   = (short*)(ws + ((size_t)64 << 20));        // 32MiB weight planes
  char*  Cbuf = ws + ((size_t)96 << 20);                  // chunk scratch
  const int Rrows = (ws_size >= ((size_t)232 << 20)) ? 16384
                  : (ws_size >= ((size_t)160 << 20)) ? 8192
                  : (ws_size >= ((size_t)128 << 20)) ? 4096 : 2048;

  const int SZ_QKV = 512 * 1536, SZ_P = 512 * 512, SZ_F1 = 512 * 2048, SZ_F2 = 2048 * 512;
  const int PB = (SZ_QKV + SZ_P + SZ_F1 + SZ_F2) * 2;
  short* cbH = Wb + (size_t)2 * PB;
  short* cbL = cbH + 4096 * 512;

  // ---- one-time (per launch) weight transpose + split ----
  for (int blk = 0; blk < 2; blk++) {
    short* base = Wb + (size_t)blk * PB;
    short* qH = base;          short* qL = qH + SZ_QKV;
    short* pH = qL + SZ_QKV;   short* pL = pH + SZ_P;
    short* f1H = pL + SZ_P;    short* f1L = f1H + SZ_F1;
    short* f2H = f1L + SZ_F1;  short* f2L = f2H + SZ_F2;
    wconvT_kernel<<<dim3(48, 16), dim3(32, 8), 0, stream>>>(qkvw + (size_t)blk * SZ_QKV, qH, qL, 512, 1536);
    wconvT_kernel<<<dim3(16, 16), dim3(32, 8), 0, stream>>>(pw + (size_t)blk * SZ_P, pH, pL, 512, 512);
    wconvT_kernel<<<dim3(64, 16), dim3(32, 8), 0, stream>>>(f1w + (size_t)blk * SZ_F1, f1H, f1L, 512, 2048);
    wconvT_kernel<<<dim3(16, 64), dim3(32, 8), 0, stream>>>(f2w + (size_t)blk * SZ_F2, f2H, f2L, 2048, 512);
  }
  wconv_kernel<<<2048, 256, 0, stream>>>(cb, cbH, cbL);

  const int nch = ROWS / Rrows;
  for (int blk = 0; blk < 2; blk++) {
    short* base = Wb + (size_t)blk * PB;
    short* qH = base;          short* qL = qH + SZ_QKV;
    short* pH = qL + SZ_QKV;   short* pL = pH + SZ_P;
    short* f1H = pL + SZ_P;    short* f1L = f1H + SZ_F1;
    short* f2H = f1L + SZ_F1;  short* f2L = f2H + SZ_F2;
    const float* xcur = blk ? (const float*)Abuf : x_in;
    int shift = blk ? 4 : 0;

    // LN1 + shift + window partition -> hi/lo planes (windowed order)
    ln_split_kernel<<<8192, 256, 0, stream>>>(xcur, Hbuf, Lbuf, n1g + blk * 512, n1b + blk * 512, shift, 1);

    // qkv GEMM (fp32 out) + attention (writes planes back in place)
    float* Cq = (float*)Cbuf;
    for (int ch = 0; ch < nch; ch++) {
      int r0 = ch * Rrows;
      mgemm<0><<<dim3(Rrows / 128, 12), 512, 0, stream>>>(
          Hbuf + (size_t)r0 * 512, Lbuf + (size_t)r0 * 512, qH, qL, 512,
          qkvb + blk * 1536, Cq, nullptr, nullptr, 1536,
          nullptr, 0, 0, 0);
      attn_kernel<<<dim3(Rrows / 64, 8), 256, 0, stream>>>(
          Cq, rpb + blk * 1800, Hbuf, Lbuf, r0 >> 6, shift);
    }

    // proj + window reverse + unshift + residual -> Abuf (fp32)
    mgemm<2><<<dim3(256, 4), 512, 0, stream>>>(
        Hbuf, Lbuf, pH, pL, 512, pb + blk * 512,
        Abuf, nullptr, nullptr, 512,
        blk ? (const float*)Abuf : x_in, 0, 1, shift);

    // LN2 -> planes (identity order)
    ln_split_kernel<<<8192, 256, 0, stream>>>(Abuf, Hbuf, Lbuf, n2g + blk * 512, n2b + blk * 512, 0, 0);

    // MLP; blk==1 fc2 also emits h/l planes (fused split for VQ)
    short* gh = (short*)Cbuf;
    short* gl = gh + (size_t)Rrows * 2048;
    for (int ch = 0; ch < nch; ch++) {
      int r0 = ch * Rrows;
      mgemm<1><<<dim3(Rrows / 128, 16), 512, 0, stream>>>(
          Hbuf + (size_t)r0 * 512, Lbuf + (size_t)r0 * 512, f1H, f1L, 512,
          f1b + blk * 2048, nullptr, gh, gl, 2048,
          nullptr, 0, 0, 0);
      if (blk == 0) {
        mgemm<2><<<dim3(Rrows / 128, 4), 512, 0, stream>>>(
            gh, gl, f2H, f2L, 2048, f2b_ + blk * 512,
            Abuf, nullptr, nullptr, 512,
            Abuf, r0, 0, 0);
      } else {
        mgemm<4><<<dim3(Rrows / 128, 4), 512, 0, stream>>>(
            gh, gl, f2H, f2L, 2048, f2b_ + blk * 512,
            Abuf, Hbuf, Lbuf, 512,
            Abuf, r0, 0, 0);
      }
    }
  }

  // ---- VQ: approx top-2/tile via single-pass fp16 GEMM, exact rescore ----
  float*    c2  = (float*)Cbuf;                              // 16 KB
  unsigned* pkb = (unsigned*)(Cbuf + ((size_t)64 << 10));    // 8 MiB: 32768 x 64 keys
  rowss_kernel<<<1024, 256, 0, stream>>>(cb, c2, 4096);
  vqgemm<<<8192, 256, 0, stream>>>(Hbuf, cbH, c2, pkb);
  vq_out_kernel<<<8192, 256, 0, stream>>>(pkb, Abuf, cb, outq, outidx);
}

// Round 9
// 2342.578 us; speedup vs baseline: 3.6945x; 1.0347x over previous
//
#include <hip/hip_runtime.h>
#include <math.h>

#define DEV __device__ __forceinline__

typedef __attribute__((ext_vector_type(8))) _Float16 f16x8;
typedef __attribute__((ext_vector_type(8))) short short8;
typedef __attribute__((ext_vector_type(4))) float f32x4;

namespace {

constexpr int C = 512;
constexpr int ROWS = 32768;   // B * L
constexpr float LSCALE = 2048.0f;        // lo-plane pre-scale (2^11)
constexpr float LINV   = 1.0f / 2048.0f;
constexpr float F16MIN = 6.1035156e-5f;  // fp16 min normal

// fp32 -> fp16 hi/lo split. h = RTN(x) (flushed to 0 below normal range),
// l = RTN((x - h) * 2^11). Ensures all MFMA inputs are 0 or normal fp16.
DEV void f2hsplit(float x, short& hs, short& ls) {
  _Float16 h = (_Float16)x;
  float hf = (float)h;
  if (fabsf(hf) < F16MIN) { h = (_Float16)0.0f; hf = 0.f; }
  _Float16 l = (_Float16)((x - hf) * LSCALE);
  if (fabsf((float)l) < F16MIN) l = (_Float16)0.0f;
  hs = __builtin_bit_cast(short, h);
  ls = __builtin_bit_cast(short, l);
}

DEV unsigned umn(unsigned a, unsigned b) { return a < b ? a : b; }
DEV unsigned umx(unsigned a, unsigned b) { return a > b ? a : b; }

// monotone key: high 20 bits = sign-flipped fp32 distance, low 12 = col idx.
DEV unsigned packkey(float d, int col) {
  unsigned u = __builtin_bit_cast(unsigned, d);
  u = (u & 0x80000000u) ? ~u : (u | 0x80000000u);
  return (u & 0xFFFFF000u) | (unsigned)col;
}
DEV float unpackd(unsigned k) {
  unsigned u = (k & 0x80000000u) ? (k ^ 0x80000000u) : ~k;
  return __builtin_bit_cast(float, u);
}

// windowed row r -> flat row in (b, y, x) order, for roll by `shift`.
DEV int rowmap(int r, int shift) {
  int b  = r >> 10;
  int w  = (r >> 6) & 15;
  int wy = w >> 2, wx = w & 3;
  int ii = r & 63;
  int iy = ii >> 3, ix = ii & 7;
  int y = (wy * 8 + iy + shift) & 31;
  int x = (wx * 8 + ix + shift) & 31;
  return (b << 10) + (y << 5) + x;
}

DEV int region(int y) { return (y < 24) ? 0 : ((y < 28) ? 1 : 2); }

typedef __attribute__((address_space(1))) const unsigned int gu32;
typedef __attribute__((address_space(3))) unsigned int lu32;
DEV void gload16(const void* g, void* l) {
  __builtin_amdgcn_global_load_lds((gu32*)g, (lu32*)l, 16, 0, 0);
}

// ---------------- LayerNorm -> fp16 hi/lo planes ---------------------------
__global__ __launch_bounds__(256) void ln_split_kernel(
    const float* __restrict__ src, short* __restrict__ Hp, short* __restrict__ Lp,
    const float* __restrict__ g, const float* __restrict__ b,
    int shift, int windowed) {
  int wid  = (blockIdx.x * 256 + threadIdx.x) >> 6;
  int lane = threadIdx.x & 63;
  if (wid >= ROWS) return;
  int srcRow = windowed ? rowmap(wid, shift) : wid;
  const float* s = src + (size_t)srcRow * C + lane * 8;
  float v[8];
  *(float4*)(v)     = *(const float4*)(s);
  *(float4*)(v + 4) = *(const float4*)(s + 4);
  float sum = 0.f;
#pragma unroll
  for (int j = 0; j < 8; j++) sum += v[j];
#pragma unroll
  for (int o = 32; o >= 1; o >>= 1) sum += __shfl_xor(sum, o);
  float mu = sum * (1.0f / 512.0f);
  float vs = 0.f;
#pragma unroll
  for (int j = 0; j < 8; j++) { float d = v[j] - mu; vs += d * d; }
#pragma unroll
  for (int o = 32; o >= 1; o >>= 1) vs += __shfl_xor(vs, o);
  float rs = rsqrtf(vs * (1.0f / 512.0f) + 1e-5f);
  float gg[8], bb[8];
  *(float4*)gg       = *(const float4*)&g[lane * 8];
  *(float4*)(gg + 4) = *(const float4*)&g[lane * 8 + 4];
  *(float4*)bb       = *(const float4*)&b[lane * 8];
  *(float4*)(bb + 4) = *(const float4*)&b[lane * 8 + 4];
  short8 hv, lv;
#pragma unroll
  for (int j = 0; j < 8; j++) {
    float o8 = (v[j] - mu) * rs * gg[j] + bb[j];
    short hh, ll;
    f2hsplit(o8, hh, ll);
    hv[j] = hh; lv[j] = ll;
  }
  *(short8*)&Hp[(size_t)wid * C + lane * 8] = hv;
  *(short8*)&Lp[(size_t)wid * C + lane * 8] = lv;
}

// ---------------- row sum of squares (codebook) ----------------------------
__global__ __launch_bounds__(256) void rowss_kernel(
    const float* __restrict__ src, float* __restrict__ dst, int nrows) {
  int wid  = (blockIdx.x * 256 + threadIdx.x) >> 6;
  int lane = threadIdx.x & 63;
  if (wid >= nrows) return;
  const float* s = src + (size_t)wid * C + lane * 8;
  float4 a  = *(const float4*)s;
  float4 b4 = *(const float4*)(s + 4);
  float sum = a.x*a.x + a.y*a.y + a.z*a.z + a.w*a.w
            + b4.x*b4.x + b4.y*b4.y + b4.z*b4.z + b4.w*b4.w;
#pragma unroll
  for (int o = 32; o >= 1; o >>= 1) sum += __shfl_xor(sum, o);
  if (lane == 0) dst[wid] = sum;
}

// ---------------- weight transpose + split: W(K,N) -> H/L (N,K) ------------
__global__ __launch_bounds__(256) void wconvT_kernel(
    const float* __restrict__ W, short* __restrict__ Hp, short* __restrict__ Lp,
    int K, int N) {
  __shared__ float t[32][33];
  int tx = threadIdx.x, ty = threadIdx.y;
  int n0 = blockIdx.x * 32, k0 = blockIdx.y * 32;
#pragma unroll
  for (int r = 0; r < 4; r++) {
    int k = ty + r * 8;
    t[k][tx] = W[(size_t)(k0 + k) * N + n0 + tx];
  }
  __syncthreads();
#pragma unroll
  for (int r = 0; r < 4; r++) {
    int n = ty + r * 8;
    short h, l;
    f2hsplit(t[tx][n], h, l);
    Hp[(size_t)(n0 + n) * K + k0 + tx] = h;
    Lp[(size_t)(n0 + n) * K + k0 + tx] = l;
  }
}

// ---------------- codebook split (already N-major) -------------------------
__global__ __launch_bounds__(256) void wconv_kernel(
    const float* __restrict__ W, short* __restrict__ Hp, short* __restrict__ Lp) {
  size_t i = ((size_t)blockIdx.x * 256 + threadIdx.x) * 4;
  float4 a = *(const float4*)&W[i];
  float v[4] = {a.x, a.y, a.z, a.w};
  short hv[4], lv[4];
#pragma unroll
  for (int j = 0; j < 4; j++) f2hsplit(v[j], hv[j], lv[j]);
  *(short4*)&Hp[i] = *(short4*)hv;
  *(short4*)&Lp[i] = *(short4*)lv;
}

// -- fp16-pair MFMA GEMM, 128x128 tile, BK=32, 8 waves, LDS double-buffer ---
// A planes [M][K], B planes [N][K]; C = A * B^T (+ epilogue).
// acc = accH(h*h) + 2^-11 * accL(h*lw + la*h); la/lw are pre-scaled by 2^11.
// min-2-phase: stage next K-tile, compute current, one barrier per step.
// EPI: 0 = fp32 out+bias (qkv); 1 = gelu -> hi/lo planes (fc1);
//      2 = +bias+resid fp32 (proj/fc2); 4 = EPI2 + h/l plane store
template <int EPI>
__global__ __launch_bounds__(512) void mgemm(
    const short* __restrict__ Ah, const short* __restrict__ Al,
    const short* __restrict__ Bh, const short* __restrict__ Bl,
    const int K, const float* __restrict__ bias,
    float* __restrict__ outF, short* __restrict__ outH, short* __restrict__ outL,
    const int ldo,
    const float* __restrict__ resid, const int rowOff, const int perm, const int shift) {
  __shared__ short lds[32768];   // 2 buffers x (Ah|Bh|Al|Bl) 128x32 fp16 tiles
  const int m0 = blockIdx.x * 128, n0 = blockIdx.y * 128;
  const int t  = threadIdx.x;
  const int wv = t >> 6, ln = t & 63;
  const int wr = (wv >> 2) * 64, wc = (wv & 3) * 32;   // wave tile 64x32
  const int l15 = ln & 15, l4 = ln >> 4;

  f32x4 accH[4][2], accL[4][2];
#pragma unroll
  for (int mf = 0; mf < 4; mf++)
#pragma unroll
    for (int nf = 0; nf < 2; nf++) {
      accH[mf][nf] = (f32x4){0.f, 0.f, 0.f, 0.f};
      accL[mf][nf] = (f32x4){0.f, 0.f, 0.f, 0.f};
    }

  const int srow = ln >> 2;                              // row within 16-row chunk
  const int scol = ((ln & 3) ^ ((ln >> 3) & 3)) * 8;     // pre-swizzled source chunk

  auto stage = [&](int buf, int k0) {
    short* b = lds + buf * 16384;
    size_t ra = (size_t)(m0 + wv * 16 + srow) * K + k0 + scol;
    size_t rb = (size_t)(n0 + wv * 16 + srow) * K + k0 + scol;
    gload16(Ah + ra, b + wv * 512);
    gload16(Bh + rb, b + 4096 + wv * 512);
    gload16(Al + ra, b + 8192 + wv * 512);
    gload16(Bl + rb, b + 12288 + wv * 512);
  };
  auto frag = [&](const short* lt, int rbase) -> f16x8 {
    int r = rbase + l15;
    int kc = l4 ^ ((r >> 1) & 3);
    return *(const f16x8*)(lt + (r >> 4) * 512 + (r & 15) * 32 + kc * 8);
  };

  stage(0, 0);
  __syncthreads();
  int cur = 0;
  for (int k0 = 0; k0 < K; k0 += 32) {
    if (k0 + 32 < K) stage(cur ^ 1, k0 + 32);
    const short* base = lds + cur * 16384;
    const short* As_h = base;
    const short* Bs_h = base + 4096;
    const short* As_l = base + 8192;
    const short* Bs_l = base + 12288;
    f16x8 ah[4], bh[2], bl[2];
#pragma unroll
    for (int mf = 0; mf < 4; mf++) ah[mf] = frag(As_h, wr + mf * 16);
#pragma unroll
    for (int nf = 0; nf < 2; nf++) bh[nf] = frag(Bs_h, wc + nf * 16);
#pragma unroll
    for (int mf = 0; mf < 4; mf++)
#pragma unroll
      for (int nf = 0; nf < 2; nf++)
        accH[mf][nf] = __builtin_amdgcn_mfma_f32_16x16x32_f16(ah[mf], bh[nf], accH[mf][nf], 0, 0, 0);
#pragma unroll
    for (int nf = 0; nf < 2; nf++) bl[nf] = frag(Bs_l, wc + nf * 16);
#pragma unroll
    for (int mf = 0; mf < 4; mf++)
#pragma unroll
      for (int nf = 0; nf < 2; nf++)
        accL[mf][nf] = __builtin_amdgcn_mfma_f32_16x16x32_f16(ah[mf], bl[nf], accL[mf][nf], 0, 0, 0);
#pragma unroll
    for (int mf = 0; mf < 4; mf++) {
      f16x8 al = frag(As_l, wr + mf * 16);
#pragma unroll
      for (int nf = 0; nf < 2; nf++)
        accL[mf][nf] = __builtin_amdgcn_mfma_f32_16x16x32_f16(al, bh[nf], accL[mf][nf], 0, 0, 0);
    }
    __syncthreads();
    cur ^= 1;
  }

  f32x4 acc[4][2];
#pragma unroll
  for (int mf = 0; mf < 4; mf++)
#pragma unroll
    for (int nf = 0; nf < 2; nf++)
#pragma unroll
      for (int r = 0; r < 4; r++)
        acc[mf][nf][r] = fmaf(accL[mf][nf][r], LINV, accH[mf][nf][r]);

  if (EPI == 0) {
#pragma unroll
    for (int mf = 0; mf < 4; mf++)
#pragma unroll
      for (int r = 0; r < 4; r++) {
        int row = m0 + wr + mf * 16 + l4 * 4 + r;
        float* op = outF + (size_t)row * ldo;
#pragma unroll
        for (int nf = 0; nf < 2; nf++) {
          int col = n0 + wc + nf * 16 + l15;
          op[col] = acc[mf][nf][r] + bias[col];
        }
      }
  } else if (EPI == 1) {
#pragma unroll
    for (int mf = 0; mf < 4; mf++)
#pragma unroll
      for (int r = 0; r < 4; r++) {
        int row = m0 + wr + mf * 16 + l4 * 4 + r;
#pragma unroll
        for (int nf = 0; nf < 2; nf++) {
          int col = n0 + wc + nf * 16 + l15;
          float v = acc[mf][nf][r] + bias[col];
          v = 0.5f * v * (1.0f + erff(v * 0.70710678118654752f));
          short h, l;
          f2hsplit(v, h, l);
          outH[(size_t)row * ldo + col] = h;
          outL[(size_t)row * ldo + col] = l;
        }
      }
  } else {  // EPI == 2 or 4
#pragma unroll
    for (int mf = 0; mf < 4; mf++)
#pragma unroll
      for (int r = 0; r < 4; r++) {
        int row = m0 + wr + mf * 16 + l4 * 4 + r;
        int orow = perm ? rowmap(row, shift) : (row + rowOff);
        const float* rp = resid + (size_t)orow * ldo;
        float* op = outF + (size_t)orow * ldo;
#pragma unroll
        for (int nf = 0; nf < 2; nf++) {
          int col = n0 + wc + nf * 16 + l15;
          float v = rp[col] + acc[mf][nf][r] + bias[col];
          op[col] = v;
          if (EPI == 4) {
            short h, l;
            f2hsplit(v, h, l);
            outH[(size_t)orow * ldo + col] = h;
            outL[(size_t)orow * ldo + col] = l;
          }
        }
      }
  }
}

// ------ VQ distance GEMM: h*h only, 128x128 tile, BK=32, 8 waves, dbuf -----
// top-2 per 128-col tile emitted as packed keys; exact rescore downstream.
__global__ __launch_bounds__(512) void vqgemm(
    const short* __restrict__ Ah, const short* __restrict__ Bh,
    const float* __restrict__ c2, unsigned* __restrict__ pk) {
  __shared__ short lds[16384];   // 2 buffers x (A|B) 128x32 fp16 tiles
  const int bid = blockIdx.x;
  const int xcd = bid & 7, idx = bid >> 3;
  const int m0 = (xcd * 32 + (idx & 31)) * 128;   // m-slab per XCD
  const int ny = idx >> 5;
  const int n0 = ny * 128;
  const int K = 512;
  const int t  = threadIdx.x;
  const int wv = t >> 6, ln = t & 63;
  const int wr = (wv >> 2) * 64, wc = (wv & 3) * 32;  // wave tile 64x32
  const int l15 = ln & 15, l4 = ln >> 4;

  f32x4 acc[4][2];
#pragma unroll
  for (int mf = 0; mf < 4; mf++)
#pragma unroll
    for (int nf = 0; nf < 2; nf++) acc[mf][nf] = (f32x4){0.f, 0.f, 0.f, 0.f};

  const int srow = ln >> 2;
  const int scol = ((ln & 3) ^ ((ln >> 3) & 3)) * 8;

  auto stage = [&](int buf, int k0) {
    short* b = lds + buf * 8192;
    size_t ra = (size_t)(m0 + wv * 16 + srow) * K + k0 + scol;
    size_t rb = (size_t)(n0 + wv * 16 + srow) * K + k0 + scol;
    gload16(Ah + ra, b + wv * 512);
    gload16(Bh + rb, b + 4096 + wv * 512);
  };
  auto frag = [&](const short* lt, int rbase) -> f16x8 {
    int r = rbase + l15;
    int kc = l4 ^ ((r >> 1) & 3);
    return *(const f16x8*)(lt + (r >> 4) * 512 + (r & 15) * 32 + kc * 8);
  };

  stage(0, 0);
  __syncthreads();
  int cur = 0;
  for (int k0 = 0; k0 < K; k0 += 32) {
    if (k0 + 32 < K) stage(cur ^ 1, k0 + 32);
    const short* base = lds + cur * 8192;
    f16x8 ah[4], bh[2];
#pragma unroll
    for (int mf = 0; mf < 4; mf++) ah[mf] = frag(base, wr + mf * 16);
#pragma unroll
    for (int nf = 0; nf < 2; nf++) bh[nf] = frag(base + 4096, wc + nf * 16);
#pragma unroll
    for (int mf = 0; mf < 4; mf++)
#pragma unroll
      for (int nf = 0; nf < 2; nf++)
        acc[mf][nf] = __builtin_amdgcn_mfma_f32_16x16x32_f16(ah[mf], bh[nf], acc[mf][nf], 0, 0, 0);
    __syncthreads();
    cur ^= 1;
  }

  // top-2 per row over this 128-col tile
  unsigned* hk = (unsigned*)(void*)lds;   // [128 rows][4 quarters][2 entries]
#pragma unroll
  for (int mf = 0; mf < 4; mf++)
#pragma unroll
    for (int r = 0; r < 4; r++) {
      int wrow = wr + mf * 16 + l4 * 4 + r;
      unsigned k1 = 0xFFFFFFFFu, k2 = 0xFFFFFFFFu;
#pragma unroll
      for (int nf = 0; nf < 2; nf++) {
        int col = n0 + wc + nf * 16 + l15;
        float d = c2[col] - 2.0f * acc[mf][nf][r];
        unsigned kk = packkey(d, col);
        if (kk < k1) { k2 = k1; k1 = kk; }
        else if (kk < k2) { k2 = kk; }
      }
      // 16-lane (same l4) top-2 butterfly over the wave's 32 cols
#pragma unroll
      for (int o = 1; o <= 8; o <<= 1) {
        unsigned b1 = (unsigned)__shfl_xor((int)k1, o);
        unsigned b2 = (unsigned)__shfl_xor((int)k2, o);
        unsigned m1 = umn(k1, b1);
        unsigned m2 = umn(umx(k1, b1), umn(k2, b2));
        k1 = m1; k2 = m2;
      }
      if (l15 == 0) {
        hk[wrow * 8 + (wv & 3) * 2 + 0] = k1;
        hk[wrow * 8 + (wv & 3) * 2 + 1] = k2;
      }
    }
  __syncthreads();
  if (t < 128) {
    unsigned q1[4], q2[4];
#pragma unroll
    for (int i = 0; i < 4; i++) {
      q1[i] = hk[t * 8 + i * 2];
      q2[i] = hk[t * 8 + i * 2 + 1];
    }
    unsigned a1 = umn(q1[0], q1[1]);
    unsigned a2 = umn(umx(q1[0], q1[1]), umn(q2[0], q2[1]));
    unsigned b1 = umn(q1[2], q1[3]);
    unsigned b2 = umn(umx(q1[2], q1[3]), umn(q2[2], q2[3]));
    unsigned m1 = umn(a1, b1);
    unsigned m2 = umn(umx(a1, b1), umn(a2, b2));
    size_t base = (size_t)(m0 + t) * 64 + ny * 2;
    pk[base + 0] = m1;
    pk[base + 1] = m2;
  }
}

// ---------------- candidate select + exact fp32 rescore + gather -----------
__global__ __launch_bounds__(256) void vq_out_kernel(
    const unsigned* __restrict__ pk, const float* __restrict__ x,
    const float* __restrict__ cb,
    float* __restrict__ outq, float* __restrict__ outidx) {
  int r = blockIdx.x * 4 + (threadIdx.x >> 6);
  int lane = threadIdx.x & 63;
  unsigned key = pk[(size_t)r * 64 + lane];
  unsigned kmin = key;
#pragma unroll
  for (int o = 32; o >= 1; o >>= 1) kmin = umn(kmin, (unsigned)__shfl_xor((int)kmin, o));
  float dmin = unpackd(kmin);
  unsigned long long mask = __ballot(unpackd(key) <= dmin + 2.0f);

  const float* xr = x + (size_t)r * C + lane * 8;
  float4 xa = *(const float4*)xr;
  float4 xb = *(const float4*)(xr + 4);

  float bestd = 3.4e38f;
  int   besti = 0x7fffffff;
  while (mask) {
    int l = __ffsll(mask) - 1;
    mask &= mask - 1;
    int col = ((unsigned)__shfl((int)key, l)) & 0xFFFu;
    const float* cr = cb + (size_t)col * C + lane * 8;
    float4 ca = *(const float4*)cr;
    float4 cb4 = *(const float4*)(cr + 4);
    float s = 0.f;
    s = fmaf(ca.x, ca.x - 2.f * xa.x, s);
    s = fmaf(ca.y, ca.y - 2.f * xa.y, s);
    s = fmaf(ca.z, ca.z - 2.f * xa.z, s);
    s = fmaf(ca.w, ca.w - 2.f * xa.w, s);
    s = fmaf(cb4.x, cb4.x - 2.f * xb.x, s);
    s = fmaf(cb4.y, cb4.y - 2.f * xb.y, s);
    s = fmaf(cb4.z, cb4.z - 2.f * xb.z, s);
    s = fmaf(cb4.w, cb4.w - 2.f * xb.w, s);
#pragma unroll
    for (int o = 32; o >= 1; o >>= 1) s += __shfl_xor(s, o);
    if (s < bestd || (s == bestd && col < besti)) { bestd = s; besti = col; }
  }
  const float4* src = (const float4*)(cb + (size_t)besti * C + lane * 8);
  float4*       dst = (float4*)(outq + (size_t)r * C + lane * 8);
  dst[0] = src[0];
  dst[1] = src[1];
  if (lane == 0) outidx[r] = (float)besti;
}

// ---------------- fused per-(window, head) attention (fp32) ----------------
__global__ __launch_bounds__(256) void attn_kernel(
    const float* __restrict__ qkv,   // chunk-local windowed rows x 1536
    const float* __restrict__ rpb,   // (225, 8)
    short* __restrict__ Hout, short* __restrict__ Lout,  // global windowed rows x 512
    int winOff, int shift) {
  int wl = blockIdx.x;
  int h  = blockIdx.y;
  int t  = threadIdx.x;
  __shared__ float q[64][64], k[64][64], v[64][64], pT[64][64];

  const float* base = qkv + (size_t)wl * 64 * 1536 + h * 64;
#pragma unroll
  for (int rep = 0; rep < 4; rep++) {
    int f = t + rep * 256;
    int i = f >> 4, dq = (f & 15) * 4;
    const float* rowp = base + (size_t)i * 1536 + dq;
    float4 qv = *(const float4*)(rowp);
    float4 kv = *(const float4*)(rowp + 512);
    float4 vv = *(const float4*)(rowp + 1024);
    q[i][dq] = qv.x * 0.125f; q[i][dq + 1] = qv.y * 0.125f;
    q[i][dq + 2] = qv.z * 0.125f; q[i][dq + 3] = qv.w * 0.125f;
    *(float4*)&k[i][dq] = kv;
    *(float4*)&v[i][dq] = vv;
  }
  __syncthreads();

  int i  = t >> 2;
  int jg = t & 3;
  int wim = (winOff + wl) & 15;
  int wy = wim >> 2, wx = wim & 3;
  int iy = i >> 3, ix = i & 7;

  float qreg[64];
#pragma unroll
  for (int d = 0; d < 64; d += 4) *(float4*)&qreg[d] = *(float4*)&q[i][d];

  int ci = 0;
  if (shift) ci = region(wy * 8 + iy) * 3 + region(wx * 8 + ix);

  float sc[16];
#pragma unroll
  for (int jj = 0; jj < 16; jj++) {
    int j = jg * 16 + jj;
    float s = 0.f;
#pragma unroll
    for (int d = 0; d < 64; d += 4) {
      float4 kv = *(float4*)&k[j][d];
      s = fmaf(qreg[d], kv.x, s);
      s = fmaf(qreg[d + 1], kv.y, s);
      s = fmaf(qreg[d + 2], kv.z, s);
      s = fmaf(qreg[d + 3], kv.w, s);
    }
    int jy = j >> 3, jx = j & 7;
    s += rpb[((iy - jy + 7) * 15 + (ix - jx + 7)) * 8 + h];
    if (shift) {
      int cj = region(wy * 8 + jy) * 3 + region(wx * 8 + jx);
      if (ci != cj) s -= 100.0f;
    }
    sc[jj] = s;
  }
  float mx = sc[0];
#pragma unroll
  for (int jj = 1; jj < 16; jj++) mx = fmaxf(mx, sc[jj]);
  mx = fmaxf(mx, __shfl_xor(mx, 1));
  mx = fmaxf(mx, __shfl_xor(mx, 2));
  float sum = 0.f;
#pragma unroll
  for (int jj = 0; jj < 16; jj++) { sc[jj] = expf(sc[jj] - mx); sum += sc[jj]; }
  sum += __shfl_xor(sum, 1);
  sum += __shfl_xor(sum, 2);
  float inv = 1.0f / sum;
#pragma unroll
  for (int jj = 0; jj < 16; jj++) pT[jg * 16 + jj][i] = sc[jj] * inv;
  __syncthreads();

  float accv[16];
#pragma unroll
  for (int dd = 0; dd < 16; dd++) accv[dd] = 0.f;
  for (int j = 0; j < 64; j++) {
    float pij = pT[j][i];
#pragma unroll
    for (int dd = 0; dd < 16; dd += 4) {
      float4 vv = *(float4*)&v[j][jg * 16 + dd];
      accv[dd]     = fmaf(pij, vv.x, accv[dd]);
      accv[dd + 1] = fmaf(pij, vv.y, accv[dd + 1]);
      accv[dd + 2] = fmaf(pij, vv.z, accv[dd + 2]);
      accv[dd + 3] = fmaf(pij, vv.w, accv[dd + 3]);
    }
  }
  size_t obase = ((size_t)(winOff + wl) * 64 + i) * 512 + h * 64 + jg * 16;
  short8 hv, lv;
#pragma unroll
  for (int half = 0; half < 2; half++) {
#pragma unroll
    for (int j = 0; j < 8; j++) {
      short hh, ll;
      f2hsplit(accv[half * 8 + j], hh, ll);
      hv[j] = hh; lv[j] = ll;
    }
    *(short8*)&Hout[obase + half * 8] = hv;
    *(short8*)&Lout[obase + half * 8] = lv;
  }
}

}  // namespace

extern "C" void kernel_launch(void* const* d_in, const int* in_sizes, int n_in,
                              void* d_out, int out_size, void* d_ws, size_t ws_size,
                              hipStream_t stream) {
  const float* x_in = (const float*)d_in[0];
  const float* n1g  = (const float*)d_in[1];
  const float* n1b  = (const float*)d_in[2];
  const float* qkvw = (const float*)d_in[3];
  const float* qkvb = (const float*)d_in[4];
  const float* rpb  = (const float*)d_in[5];
  const float* pw   = (const float*)d_in[6];
  const float* pb   = (const float*)d_in[7];
  const float* n2g  = (const float*)d_in[8];
  const float* n2b  = (const float*)d_in[9];
  const float* f1w  = (const float*)d_in[10];
  const float* f1b  = (const float*)d_in[11];
  const float* f2w  = (const float*)d_in[12];
  const float* f2b_ = (const float*)d_in[13];
  const float* cb   = (const float*)d_in[14];

  float* outq   = (float*)d_out;
  float* outidx = outq + 16777216;
  short* Hbuf = (short*)d_out;                 // hi plane: first 32MB of outq
  short* Lbuf = Hbuf + (size_t)ROWS * 512;     // lo plane: second 32MB

  char* ws = (char*)d_ws;
  float* Abuf = (float*)ws;                               // 64MiB residual stream
  short* Wb   = (short*)(ws + ((size_t)64 << 20));        // 32MiB weight planes
  char*  Cbuf = ws + ((size_t)96 << 20);                  // chunk scratch
  const int Rrows = (ws_size >= ((size_t)232 << 20)) ? 16384
                  : (ws_size >= ((size_t)160 << 20)) ? 8192
                  : (ws_size >= ((size_t)128 << 20)) ? 4096 : 2048;

  const int SZ_QKV = 512 * 1536, SZ_P = 512 * 512, SZ_F1 = 512 * 2048, SZ_F2 = 2048 * 512;
  const int PB = (SZ_QKV + SZ_P + SZ_F1 + SZ_F2) * 2;
  short* cbH = Wb + (size_t)2 * PB;
  short* cbL = cbH + 4096 * 512;

  // ---- one-time (per launch) weight transpose + split ----
  for (int blk = 0; blk < 2; blk++) {
    short* base = Wb + (size_t)blk * PB;
    short* qH = base;          short* qL = qH + SZ_QKV;
    short* pH = qL + SZ_QKV;   short* pL = pH + SZ_P;
    short* f1H = pL + SZ_P;    short* f1L = f1H + SZ_F1;
    short* f2H = f1L + SZ_F1;  short* f2L = f2H + SZ_F2;
    wconvT_kernel<<<dim3(48, 16), dim3(32, 8), 0, stream>>>(qkvw + (size_t)blk * SZ_QKV, qH, qL, 512, 1536);
    wconvT_kernel<<<dim3(16, 16), dim3(32, 8), 0, stream>>>(pw + (size_t)blk * SZ_P, pH, pL, 512, 512);
    wconvT_kernel<<<dim3(64, 16), dim3(32, 8), 0, stream>>>(f1w + (size_t)blk * SZ_F1, f1H, f1L, 512, 2048);
    wconvT_kernel<<<dim3(16, 64), dim3(32, 8), 0, stream>>>(f2w + (size_t)blk * SZ_F2, f2H, f2L, 2048, 512);
  }
  wconv_kernel<<<2048, 256, 0, stream>>>(cb, cbH, cbL);

  const int nch = ROWS / Rrows;
  for (int blk = 0; blk < 2; blk++) {
    short* base = Wb + (size_t)blk * PB;
    short* qH = base;          short* qL = qH + SZ_QKV;
    short* pH = qL + SZ_QKV;   short* pL = pH + SZ_P;
    short* f1H = pL + SZ_P;    short* f1L = f1H + SZ_F1;
    short* f2H = f1L + SZ_F1;  short* f2L = f2H + SZ_F2;
    const float* xcur = blk ? (const float*)Abuf : x_in;
    int shift = blk ? 4 : 0;

    // LN1 + shift + window partition -> hi/lo planes (windowed order)
    ln_split_kernel<<<8192, 256, 0, stream>>>(xcur, Hbuf, Lbuf, n1g + blk * 512, n1b + blk * 512, shift, 1);

    // qkv GEMM (fp32 out) + attention (writes planes back in place)
    float* Cq = (float*)Cbuf;
    for (int ch = 0; ch < nch; ch++) {
      int r0 = ch * Rrows;
      mgemm<0><<<dim3(Rrows / 128, 12), 512, 0, stream>>>(
          Hbuf + (size_t)r0 * 512, Lbuf + (size_t)r0 * 512, qH, qL, 512,
          qkvb + blk * 1536, Cq, nullptr, nullptr, 1536,
          nullptr, 0, 0, 0);
      attn_kernel<<<dim3(Rrows / 64, 8), 256, 0, stream>>>(
          Cq, rpb + blk * 1800, Hbuf, Lbuf, r0 >> 6, shift);
    }

    // proj + window reverse + unshift + residual -> Abuf (fp32)
    mgemm<2><<<dim3(256, 4), 512, 0, stream>>>(
        Hbuf, Lbuf, pH, pL, 512, pb + blk * 512,
        Abuf, nullptr, nullptr, 512,
        blk ? (const float*)Abuf : x_in, 0, 1, shift);

    // LN2 -> planes (identity order)
    ln_split_kernel<<<8192, 256, 0, stream>>>(Abuf, Hbuf, Lbuf, n2g + blk * 512, n2b + blk * 512, 0, 0);

    // MLP; blk==1 fc2 also emits h/l planes (fused split for VQ)
    short* gh = (short*)Cbuf;
    short* gl = gh + (size_t)Rrows * 2048;
    for (int ch = 0; ch < nch; ch++) {
      int r0 = ch * Rrows;
      mgemm<1><<<dim3(Rrows / 128, 16), 512, 0, stream>>>(
          Hbuf + (size_t)r0 * 512, Lbuf + (size_t)r0 * 512, f1H, f1L, 512,
          f1b + blk * 2048, nullptr, gh, gl, 2048,
          nullptr, 0, 0, 0);
      if (blk == 0) {
        mgemm<2><<<dim3(Rrows / 128, 4), 512, 0, stream>>>(
            gh, gl, f2H, f2L, 2048, f2b_ + blk * 512,
            Abuf, nullptr, nullptr, 512,
            Abuf, r0, 0, 0);
      } else {
        mgemm<4><<<dim3(Rrows / 128, 4), 512, 0, stream>>>(
            gh, gl, f2H, f2L, 2048, f2b_ + blk * 512,
            Abuf, Hbuf, Lbuf, 512,
            Abuf, r0, 0, 0);
      }
    }
  }

  // ---- VQ: approx top-2/tile via single-pass fp16 GEMM, exact rescore ----
  float*    c2  = (float*)Cbuf;                              // 16 KB
  unsigned* pkb = (unsigned*)(Cbuf + ((size_t)64 << 10));    // 8 MiB: 32768 x 64 keys
  rowss_kernel<<<1024, 256, 0, stream>>>(cb, c2, 4096);
  vqgemm<<<8192, 512, 0, stream>>>(Hbuf, cbH, c2, pkb);
  vq_out_kernel<<<8192, 256, 0, stream>>>(pkb, Abuf, cb, outq, outidx);
}

// Round 10
// 2331.451 us; speedup vs baseline: 3.7122x; 1.0048x over previous
//
#include <hip/hip_runtime.h>
#include <math.h>

#define DEV __device__ __forceinline__

typedef __attribute__((ext_vector_type(8))) _Float16 f16x8;
typedef __attribute__((ext_vector_type(8))) short short8;
typedef __attribute__((ext_vector_type(4))) float f32x4;

namespace {

constexpr int C = 512;
constexpr int ROWS = 32768;   // B * L
constexpr float LSCALE = 2048.0f;        // lo-plane pre-scale (2^11)
constexpr float LINV   = 1.0f / 2048.0f;
constexpr float F16MIN = 6.1035156e-5f;  // fp16 min normal

// fp32 -> fp16 hi/lo split. h = RTN(x) (flushed to 0 below normal range),
// l = RTN((x - h) * 2^11). Ensures all MFMA inputs are 0 or normal fp16.
DEV void f2hsplit(float x, short& hs, short& ls) {
  _Float16 h = (_Float16)x;
  float hf = (float)h;
  if (fabsf(hf) < F16MIN) { h = (_Float16)0.0f; hf = 0.f; }
  _Float16 l = (_Float16)((x - hf) * LSCALE);
  if (fabsf((float)l) < F16MIN) l = (_Float16)0.0f;
  hs = __builtin_bit_cast(short, h);
  ls = __builtin_bit_cast(short, l);
}

DEV unsigned umn(unsigned a, unsigned b) { return a < b ? a : b; }
DEV unsigned umx(unsigned a, unsigned b) { return a > b ? a : b; }

// monotone key: high 20 bits = sign-flipped fp32 distance, low 12 = col idx.
DEV unsigned packkey(float d, int col) {
  unsigned u = __builtin_bit_cast(unsigned, d);
  u = (u & 0x80000000u) ? ~u : (u | 0x80000000u);
  return (u & 0xFFFFF000u) | (unsigned)col;
}
DEV float unpackd(unsigned k) {
  unsigned u = (k & 0x80000000u) ? (k ^ 0x80000000u) : ~k;
  return __builtin_bit_cast(float, u);
}

// windowed row r -> flat row in (b, y, x) order, for roll by `shift`.
DEV int rowmap(int r, int shift) {
  int b  = r >> 10;
  int w  = (r >> 6) & 15;
  int wy = w >> 2, wx = w & 3;
  int ii = r & 63;
  int iy = ii >> 3, ix = ii & 7;
  int y = (wy * 8 + iy + shift) & 31;
  int x = (wx * 8 + ix + shift) & 31;
  return (b << 10) + (y << 5) + x;
}

DEV int region(int y) { return (y < 24) ? 0 : ((y < 28) ? 1 : 2); }

typedef __attribute__((address_space(1))) const unsigned int gu32;
typedef __attribute__((address_space(3))) unsigned int lu32;
DEV void gload16(const void* g, void* l) {
  __builtin_amdgcn_global_load_lds((gu32*)g, (lu32*)l, 16, 0, 0);
}

// ---------------- LayerNorm -> fp16 hi/lo planes ---------------------------
__global__ __launch_bounds__(256) void ln_split_kernel(
    const float* __restrict__ src, short* __restrict__ Hp, short* __restrict__ Lp,
    const float* __restrict__ g, const float* __restrict__ b,
    int shift, int windowed) {
  int wid  = (blockIdx.x * 256 + threadIdx.x) >> 6;
  int lane = threadIdx.x & 63;
  if (wid >= ROWS) return;
  int srcRow = windowed ? rowmap(wid, shift) : wid;
  const float* s = src + (size_t)srcRow * C + lane * 8;
  float v[8];
  *(float4*)(v)     = *(const float4*)(s);
  *(float4*)(v + 4) = *(const float4*)(s + 4);
  float sum = 0.f;
#pragma unroll
  for (int j = 0; j < 8; j++) sum += v[j];
#pragma unroll
  for (int o = 32; o >= 1; o >>= 1) sum += __shfl_xor(sum, o);
  float mu = sum * (1.0f / 512.0f);
  float vs = 0.f;
#pragma unroll
  for (int j = 0; j < 8; j++) { float d = v[j] - mu; vs += d * d; }
#pragma unroll
  for (int o = 32; o >= 1; o >>= 1) vs += __shfl_xor(vs, o);
  float rs = rsqrtf(vs * (1.0f / 512.0f) + 1e-5f);
  float gg[8], bb[8];
  *(float4*)gg       = *(const float4*)&g[lane * 8];
  *(float4*)(gg + 4) = *(const float4*)&g[lane * 8 + 4];
  *(float4*)bb       = *(const float4*)&b[lane * 8];
  *(float4*)(bb + 4) = *(const float4*)&b[lane * 8 + 4];
  short8 hv, lv;
#pragma unroll
  for (int j = 0; j < 8; j++) {
    float o8 = (v[j] - mu) * rs * gg[j] + bb[j];
    short hh, ll;
    f2hsplit(o8, hh, ll);
    hv[j] = hh; lv[j] = ll;
  }
  *(short8*)&Hp[(size_t)wid * C + lane * 8] = hv;
  *(short8*)&Lp[(size_t)wid * C + lane * 8] = lv;
}

// ---------------- row sum of squares (codebook) ----------------------------
__global__ __launch_bounds__(256) void rowss_kernel(
    const float* __restrict__ src, float* __restrict__ dst, int nrows) {
  int wid  = (blockIdx.x * 256 + threadIdx.x) >> 6;
  int lane = threadIdx.x & 63;
  if (wid >= nrows) return;
  const float* s = src + (size_t)wid * C + lane * 8;
  float4 a  = *(const float4*)s;
  float4 b4 = *(const float4*)(s + 4);
  float sum = a.x*a.x + a.y*a.y + a.z*a.z + a.w*a.w
            + b4.x*b4.x + b4.y*b4.y + b4.z*b4.z + b4.w*b4.w;
#pragma unroll
  for (int o = 32; o >= 1; o >>= 1) sum += __shfl_xor(sum, o);
  if (lane == 0) dst[wid] = sum;
}

// ---------------- weight transpose + split: W(K,N) -> H/L (N,K) ------------
__global__ __launch_bounds__(256) void wconvT_kernel(
    const float* __restrict__ W, short* __restrict__ Hp, short* __restrict__ Lp,
    int K, int N) {
  __shared__ float t[32][33];
  int tx = threadIdx.x, ty = threadIdx.y;
  int n0 = blockIdx.x * 32, k0 = blockIdx.y * 32;
#pragma unroll
  for (int r = 0; r < 4; r++) {
    int k = ty + r * 8;
    t[k][tx] = W[(size_t)(k0 + k) * N + n0 + tx];
  }
  __syncthreads();
#pragma unroll
  for (int r = 0; r < 4; r++) {
    int n = ty + r * 8;
    short h, l;
    f2hsplit(t[tx][n], h, l);
    Hp[(size_t)(n0 + n) * K + k0 + tx] = h;
    Lp[(size_t)(n0 + n) * K + k0 + tx] = l;
  }
}

// ---------------- codebook split (already N-major) -------------------------
__global__ __launch_bounds__(256) void wconv_kernel(
    const float* __restrict__ W, short* __restrict__ Hp, short* __restrict__ Lp) {
  size_t i = ((size_t)blockIdx.x * 256 + threadIdx.x) * 4;
  float4 a = *(const float4*)&W[i];
  float v[4] = {a.x, a.y, a.z, a.w};
  short hv[4], lv[4];
#pragma unroll
  for (int j = 0; j < 4; j++) f2hsplit(v[j], hv[j], lv[j]);
  *(short4*)&Hp[i] = *(short4*)hv;
  *(short4*)&Lp[i] = *(short4*)lv;
}

// -- fp16-pair MFMA GEMM, 128x128 tile, BK=32, 8 waves, LDS double-buffer ---
// A planes [M][K], B planes [N][K]; C = A * B^T (+ epilogue).
// acc = accH(h*h) + 2^-11 * accL(h*lw + la*h); la/lw are pre-scaled by 2^11.
// EPI: 0 = fp32 out+bias (qkv); 1 = gelu -> hi/lo planes (fc1);
//      2 = +bias+resid fp32 (proj/fc2); 4 = EPI2 + h/l plane store
template <int EPI>
__global__ __launch_bounds__(512) void mgemm(
    const short* __restrict__ Ah, const short* __restrict__ Al,
    const short* __restrict__ Bh, const short* __restrict__ Bl,
    const int K, const float* __restrict__ bias,
    float* __restrict__ outF, short* __restrict__ outH, short* __restrict__ outL,
    const int ldo,
    const float* __restrict__ resid, const int rowOff, const int perm, const int shift) {
  __shared__ short lds[32768];   // 2 buffers x (Ah|Bh|Al|Bl) 128x32 fp16 tiles
  const int m0 = blockIdx.x * 128, n0 = blockIdx.y * 128;
  const int t  = threadIdx.x;
  const int wv = t >> 6, ln = t & 63;
  const int wr = (wv >> 2) * 64, wc = (wv & 3) * 32;   // wave tile 64x32
  const int l15 = ln & 15, l4 = ln >> 4;

  f32x4 accH[4][2], accL[4][2];
#pragma unroll
  for (int mf = 0; mf < 4; mf++)
#pragma unroll
    for (int nf = 0; nf < 2; nf++) {
      accH[mf][nf] = (f32x4){0.f, 0.f, 0.f, 0.f};
      accL[mf][nf] = (f32x4){0.f, 0.f, 0.f, 0.f};
    }

  const int srow = ln >> 2;                              // row within 16-row chunk
  const int scol = ((ln & 3) ^ ((ln >> 3) & 3)) * 8;     // pre-swizzled source chunk

  auto stage = [&](int buf, int k0) {
    short* b = lds + buf * 16384;
    size_t ra = (size_t)(m0 + wv * 16 + srow) * K + k0 + scol;
    size_t rb = (size_t)(n0 + wv * 16 + srow) * K + k0 + scol;
    gload16(Ah + ra, b + wv * 512);
    gload16(Bh + rb, b + 4096 + wv * 512);
    gload16(Al + ra, b + 8192 + wv * 512);
    gload16(Bl + rb, b + 12288 + wv * 512);
  };
  auto frag = [&](const short* lt, int rbase) -> f16x8 {
    int r = rbase + l15;
    int kc = l4 ^ ((r >> 1) & 3);
    return *(const f16x8*)(lt + (r >> 4) * 512 + (r & 15) * 32 + kc * 8);
  };

  stage(0, 0);
  __syncthreads();
  int cur = 0;
  for (int k0 = 0; k0 < K; k0 += 32) {
    if (k0 + 32 < K) stage(cur ^ 1, k0 + 32);
    const short* base = lds + cur * 16384;
    const short* As_h = base;
    const short* Bs_h = base + 4096;
    const short* As_l = base + 8192;
    const short* Bs_l = base + 12288;
    f16x8 ah[4], bh[2], bl[2];
#pragma unroll
    for (int mf = 0; mf < 4; mf++) ah[mf] = frag(As_h, wr + mf * 16);
#pragma unroll
    for (int nf = 0; nf < 2; nf++) bh[nf] = frag(Bs_h, wc + nf * 16);
#pragma unroll
    for (int mf = 0; mf < 4; mf++)
#pragma unroll
      for (int nf = 0; nf < 2; nf++)
        accH[mf][nf] = __builtin_amdgcn_mfma_f32_16x16x32_f16(ah[mf], bh[nf], accH[mf][nf], 0, 0, 0);
#pragma unroll
    for (int nf = 0; nf < 2; nf++) bl[nf] = frag(Bs_l, wc + nf * 16);
#pragma unroll
    for (int mf = 0; mf < 4; mf++)
#pragma unroll
      for (int nf = 0; nf < 2; nf++)
        accL[mf][nf] = __builtin_amdgcn_mfma_f32_16x16x32_f16(ah[mf], bl[nf], accL[mf][nf], 0, 0, 0);
#pragma unroll
    for (int mf = 0; mf < 4; mf++) {
      f16x8 al = frag(As_l, wr + mf * 16);
#pragma unroll
      for (int nf = 0; nf < 2; nf++)
        accL[mf][nf] = __builtin_amdgcn_mfma_f32_16x16x32_f16(al, bh[nf], accL[mf][nf], 0, 0, 0);
    }
    __syncthreads();
    cur ^= 1;
  }

  f32x4 acc[4][2];
#pragma unroll
  for (int mf = 0; mf < 4; mf++)
#pragma unroll
    for (int nf = 0; nf < 2; nf++)
#pragma unroll
      for (int r = 0; r < 4; r++)
        acc[mf][nf][r] = fmaf(accL[mf][nf][r], LINV, accH[mf][nf][r]);

  if (EPI == 0) {
#pragma unroll
    for (int mf = 0; mf < 4; mf++)
#pragma unroll
      for (int r = 0; r < 4; r++) {
        int row = m0 + wr + mf * 16 + l4 * 4 + r;
        float* op = outF + (size_t)row * ldo;
#pragma unroll
        for (int nf = 0; nf < 2; nf++) {
          int col = n0 + wc + nf * 16 + l15;
          op[col] = acc[mf][nf][r] + bias[col];
        }
      }
  } else if (EPI == 1) {
#pragma unroll
    for (int mf = 0; mf < 4; mf++)
#pragma unroll
      for (int r = 0; r < 4; r++) {
        int row = m0 + wr + mf * 16 + l4 * 4 + r;
#pragma unroll
        for (int nf = 0; nf < 2; nf++) {
          int col = n0 + wc + nf * 16 + l15;
          float v = acc[mf][nf][r] + bias[col];
          v = 0.5f * v * (1.0f + erff(v * 0.70710678118654752f));
          short h, l;
          f2hsplit(v, h, l);
          outH[(size_t)row * ldo + col] = h;
          outL[(size_t)row * ldo + col] = l;
        }
      }
  } else {  // EPI == 2 or 4
#pragma unroll
    for (int mf = 0; mf < 4; mf++)
#pragma unroll
      for (int r = 0; r < 4; r++) {
        int row = m0 + wr + mf * 16 + l4 * 4 + r;
        int orow = perm ? rowmap(row, shift) : (row + rowOff);
        const float* rp = resid + (size_t)orow * ldo;
        float* op = outF + (size_t)orow * ldo;
#pragma unroll
        for (int nf = 0; nf < 2; nf++) {
          int col = n0 + wc + nf * 16 + l15;
          float v = rp[col] + acc[mf][nf][r] + bias[col];
          op[col] = v;
          if (EPI == 4) {
            short h, l;
            f2hsplit(v, h, l);
            outH[(size_t)orow * ldo + col] = h;
            outL[(size_t)orow * ldo + col] = l;
          }
        }
      }
  }
}

// -- VQ distance GEMM: h*h only, block 128x256, 8 waves of 64x64, BK=32 -----
// 4x4 fragment reuse: 8 frag reads per 16 MFMA. Single-buffer, 2 barriers.
// top-2 per 256-col tile emitted as packed keys; exact rescore downstream.
__global__ __launch_bounds__(512) void vqgemm(
    const short* __restrict__ Ah, const short* __restrict__ Bh,
    const float* __restrict__ c2, unsigned* __restrict__ pk) {
  __shared__ short lds[12288];   // A 128x32 (8 chunks) | B 256x32 (16 chunks)
  const int bid = blockIdx.x;
  const int xcd = bid & 7, idx = bid >> 3;
  const int m0 = (xcd * 32 + (idx & 31)) * 128;   // m-slab per XCD
  const int ny = idx >> 5;                        // 0..15
  const int n0 = ny * 256;
  const int K = 512;
  const int t  = threadIdx.x;
  const int wv = t >> 6, ln = t & 63;
  const int wr = (wv >> 2) * 64, wc = (wv & 3) * 64;  // wave tile 64x64
  const int l15 = ln & 15, l4 = ln >> 4;

  f32x4 acc[4][4];
#pragma unroll
  for (int mf = 0; mf < 4; mf++)
#pragma unroll
    for (int nf = 0; nf < 4; nf++) acc[mf][nf] = (f32x4){0.f, 0.f, 0.f, 0.f};

  const int srow = ln >> 2;
  const int scol = ((ln & 3) ^ ((ln >> 3) & 3)) * 8;

  short* As = lds;            // 8 chunks
  short* Bs = lds + 4096;     // 16 chunks

  auto frag = [&](const short* lt, int rbase) -> f16x8 {
    int r = rbase + l15;
    int kc = l4 ^ ((r >> 1) & 3);
    return *(const f16x8*)(lt + (r >> 4) * 512 + (r & 15) * 32 + kc * 8);
  };

  for (int k0 = 0; k0 < K; k0 += 32) {
#pragma unroll
    for (int q = 0; q < 3; q++) {
      int s = wv * 3 + q;                 // 0..23: 8 A chunks then 16 B chunks
      int isA = (s < 8);
      int c = isA ? s : (s - 8);
      const short* src = isA ? Ah : Bh;
      short* dst = (isA ? As : Bs) + c * 512;
      int rowbase = (isA ? m0 : n0) + c * 16;
      size_t ga = (size_t)(rowbase + srow) * K + k0 + scol;
      gload16(src + ga, dst);
    }
    __syncthreads();
    f16x8 ah[4], bh[4];
#pragma unroll
    for (int mf = 0; mf < 4; mf++) ah[mf] = frag(As, wr + mf * 16);
#pragma unroll
    for (int nf = 0; nf < 4; nf++) bh[nf] = frag(Bs, wc + nf * 16);
#pragma unroll
    for (int mf = 0; mf < 4; mf++)
#pragma unroll
      for (int nf = 0; nf < 4; nf++)
        acc[mf][nf] = __builtin_amdgcn_mfma_f32_16x16x32_f16(ah[mf], bh[nf], acc[mf][nf], 0, 0, 0);
    __syncthreads();
  }

  // top-2 per row over this 256-col tile
  unsigned* hk = (unsigned*)(void*)lds;   // [128 rows][4 nwaves][2] = 4 KB
#pragma unroll
  for (int mf = 0; mf < 4; mf++)
#pragma unroll
    for (int r = 0; r < 4; r++) {
      int wrow = wr + mf * 16 + l4 * 4 + r;
      unsigned k1 = 0xFFFFFFFFu, k2 = 0xFFFFFFFFu;
#pragma unroll
      for (int nf = 0; nf < 4; nf++) {
        int col = n0 + wc + nf * 16 + l15;
        float d = c2[col] - 2.0f * acc[mf][nf][r];
        unsigned kk = packkey(d, col);
        if (kk < k1) { k2 = k1; k1 = kk; }
        else if (kk < k2) { k2 = kk; }
      }
      // 16-lane (same l4 = same row) top-2 butterfly over the wave's 64 cols
#pragma unroll
      for (int o = 1; o <= 8; o <<= 1) {
        unsigned b1 = (unsigned)__shfl_xor((int)k1, o);
        unsigned b2 = (unsigned)__shfl_xor((int)k2, o);
        unsigned m1 = umn(k1, b1);
        unsigned m2 = umn(umx(k1, b1), umn(k2, b2));
        k1 = m1; k2 = m2;
      }
      if (l15 == 0) {
        hk[wrow * 8 + (wv & 3) * 2 + 0] = k1;
        hk[wrow * 8 + (wv & 3) * 2 + 1] = k2;
      }
    }
  __syncthreads();
  if (t < 128) {
    unsigned q1[4], q2[4];
#pragma unroll
    for (int i = 0; i < 4; i++) {
      q1[i] = hk[t * 8 + i * 2];
      q2[i] = hk[t * 8 + i * 2 + 1];
    }
    unsigned a1 = umn(q1[0], q1[1]);
    unsigned a2 = umn(umx(q1[0], q1[1]), umn(q2[0], q2[1]));
    unsigned b1 = umn(q1[2], q1[3]);
    unsigned b2 = umn(umx(q1[2], q1[3]), umn(q2[2], q2[3]));
    unsigned m1 = umn(a1, b1);
    unsigned m2 = umn(umx(a1, b1), umn(a2, b2));
    size_t base = (size_t)(m0 + t) * 32 + ny * 2;
    pk[base + 0] = m1;
    pk[base + 1] = m2;
  }
}

// ---------------- candidate select + exact fp32 rescore + gather -----------
__global__ __launch_bounds__(256) void vq_out_kernel(
    const unsigned* __restrict__ pk, const float* __restrict__ x,
    const float* __restrict__ cb,
    float* __restrict__ outq, float* __restrict__ outidx) {
  int r = blockIdx.x * 4 + (threadIdx.x >> 6);
  int lane = threadIdx.x & 63;
  unsigned key = (lane < 32) ? pk[(size_t)r * 32 + lane] : 0xFFFFFFFFu;
  unsigned kmin = key;
#pragma unroll
  for (int o = 32; o >= 1; o >>= 1) kmin = umn(kmin, (unsigned)__shfl_xor((int)kmin, o));
  float dmin = unpackd(kmin);
  unsigned long long mask = __ballot(lane < 32 && unpackd(key) <= dmin + 2.0f);

  const float* xr = x + (size_t)r * C + lane * 8;
  float4 xa = *(const float4*)xr;
  float4 xb = *(const float4*)(xr + 4);

  float bestd = 3.4e38f;
  int   besti = 0x7fffffff;
  while (mask) {
    int l = __ffsll(mask) - 1;
    mask &= mask - 1;
    int col = ((unsigned)__shfl((int)key, l)) & 0xFFFu;
    const float* cr = cb + (size_t)col * C + lane * 8;
    float4 ca = *(const float4*)cr;
    float4 cb4 = *(const float4*)(cr + 4);
    float s = 0.f;
    s = fmaf(ca.x, ca.x - 2.f * xa.x, s);
    s = fmaf(ca.y, ca.y - 2.f * xa.y, s);
    s = fmaf(ca.z, ca.z - 2.f * xa.z, s);
    s = fmaf(ca.w, ca.w - 2.f * xa.w, s);
    s = fmaf(cb4.x, cb4.x - 2.f * xb.x, s);
    s = fmaf(cb4.y, cb4.y - 2.f * xb.y, s);
    s = fmaf(cb4.z, cb4.z - 2.f * xb.z, s);
    s = fmaf(cb4.w, cb4.w - 2.f * xb.w, s);
#pragma unroll
    for (int o = 32; o >= 1; o >>= 1) s += __shfl_xor(s, o);
    if (s < bestd || (s == bestd && col < besti)) { bestd = s; besti = col; }
  }
  const float4* src = (const float4*)(cb + (size_t)besti * C + lane * 8);
  float4*       dst = (float4*)(outq + (size_t)r * C + lane * 8);
  dst[0] = src[0];
  dst[1] = src[1];
  if (lane == 0) outidx[r] = (float)besti;
}

// ---------------- fused per-(window, head) attention (fp32) ----------------
__global__ __launch_bounds__(256) void attn_kernel(
    const float* __restrict__ qkv,   // chunk-local windowed rows x 1536
    const float* __restrict__ rpb,   // (225, 8)
    short* __restrict__ Hout, short* __restrict__ Lout,  // global windowed rows x 512
    int winOff, int shift) {
  int wl = blockIdx.x;
  int h  = blockIdx.y;
  int t  = threadIdx.x;
  __shared__ float q[64][64], k[64][64], v[64][64], pT[64][64];

  const float* base = qkv + (size_t)wl * 64 * 1536 + h * 64;
#pragma unroll
  for (int rep = 0; rep < 4; rep++) {
    int f = t + rep * 256;
    int i = f >> 4, dq = (f & 15) * 4;
    const float* rowp = base + (size_t)i * 1536 + dq;
    float4 qv = *(const float4*)(rowp);
    float4 kv = *(const float4*)(rowp + 512);
    float4 vv = *(const float4*)(rowp + 1024);
    q[i][dq] = qv.x * 0.125f; q[i][dq + 1] = qv.y * 0.125f;
    q[i][dq + 2] = qv.z * 0.125f; q[i][dq + 3] = qv.w * 0.125f;
    *(float4*)&k[i][dq] = kv;
    *(float4*)&v[i][dq] = vv;
  }
  __syncthreads();

  int i  = t >> 2;
  int jg = t & 3;
  int wim = (winOff + wl) & 15;
  int wy = wim >> 2, wx = wim & 3;
  int iy = i >> 3, ix = i & 7;

  float qreg[64];
#pragma unroll
  for (int d = 0; d < 64; d += 4) *(float4*)&qreg[d] = *(float4*)&q[i][d];

  int ci = 0;
  if (shift) ci = region(wy * 8 + iy) * 3 + region(wx * 8 + ix);

  float sc[16];
#pragma unroll
  for (int jj = 0; jj < 16; jj++) {
    int j = jg * 16 + jj;
    float s = 0.f;
#pragma unroll
    for (int d = 0; d < 64; d += 4) {
      float4 kv = *(float4*)&k[j][d];
      s = fmaf(qreg[d], kv.x, s);
      s = fmaf(qreg[d + 1], kv.y, s);
      s = fmaf(qreg[d + 2], kv.z, s);
      s = fmaf(qreg[d + 3], kv.w, s);
    }
    int jy = j >> 3, jx = j & 7;
    s += rpb[((iy - jy + 7) * 15 + (ix - jx + 7)) * 8 + h];
    if (shift) {
      int cj = region(wy * 8 + jy) * 3 + region(wx * 8 + jx);
      if (ci != cj) s -= 100.0f;
    }
    sc[jj] = s;
  }
  float mx = sc[0];
#pragma unroll
  for (int jj = 1; jj < 16; jj++) mx = fmaxf(mx, sc[jj]);
  mx = fmaxf(mx, __shfl_xor(mx, 1));
  mx = fmaxf(mx, __shfl_xor(mx, 2));
  float sum = 0.f;
#pragma unroll
  for (int jj = 0; jj < 16; jj++) { sc[jj] = expf(sc[jj] - mx); sum += sc[jj]; }
  sum += __shfl_xor(sum, 1);
  sum += __shfl_xor(sum, 2);
  float inv = 1.0f / sum;
#pragma unroll
  for (int jj = 0; jj < 16; jj++) pT[jg * 16 + jj][i] = sc[jj] * inv;
  __syncthreads();

  float accv[16];
#pragma unroll
  for (int dd = 0; dd < 16; dd++) accv[dd] = 0.f;
  for (int j = 0; j < 64; j++) {
    float pij = pT[j][i];
#pragma unroll
    for (int dd = 0; dd < 16; dd += 4) {
      float4 vv = *(float4*)&v[j][jg * 16 + dd];
      accv[dd]     = fmaf(pij, vv.x, accv[dd]);
      accv[dd + 1] = fmaf(pij, vv.y, accv[dd + 1]);
      accv[dd + 2] = fmaf(pij, vv.z, accv[dd + 2]);
      accv[dd + 3] = fmaf(pij, vv.w, accv[dd + 3]);
    }
  }
  size_t obase = ((size_t)(winOff + wl) * 64 + i) * 512 + h * 64 + jg * 16;
  short8 hv, lv;
#pragma unroll
  for (int half = 0; half < 2; half++) {
#pragma unroll
    for (int j = 0; j < 8; j++) {
      short hh, ll;
      f2hsplit(accv[half * 8 + j], hh, ll);
      hv[j] = hh; lv[j] = ll;
    }
    *(short8*)&Hout[obase + half * 8] = hv;
    *(short8*)&Lout[obase + half * 8] = lv;
  }
}

}  // namespace

extern "C" void kernel_launch(void* const* d_in, const int* in_sizes, int n_in,
                              void* d_out, int out_size, void* d_ws, size_t ws_size,
                              hipStream_t stream) {
  const float* x_in = (const float*)d_in[0];
  const float* n1g  = (const float*)d_in[1];
  const float* n1b  = (const float*)d_in[2];
  const float* qkvw = (const float*)d_in[3];
  const float* qkvb = (const float*)d_in[4];
  const float* rpb  = (const float*)d_in[5];
  const float* pw   = (const float*)d_in[6];
  const float* pb   = (const float*)d_in[7];
  const float* n2g  = (const float*)d_in[8];
  const float* n2b  = (const float*)d_in[9];
  const float* f1w  = (const float*)d_in[10];
  const float* f1b  = (const float*)d_in[11];
  const float* f2w  = (const float*)d_in[12];
  const float* f2b_ = (const float*)d_in[13];
  const float* cb   = (const float*)d_in[14];

  float* outq   = (float*)d_out;
  float* outidx = outq + 16777216;
  short* Hbuf = (short*)d_out;                 // hi plane: first 32MB of outq
  short* Lbuf = Hbuf + (size_t)ROWS * 512;     // lo plane: second 32MB

  char* ws = (char*)d_ws;
  float* Abuf = (float*)ws;                               // 64MiB residual stream
  short* Wb   = (short*)(ws + ((size_t)64 << 20));        // 32MiB weight planes
  char*  Cbuf = ws + ((size_t)96 << 20);                  // chunk scratch
  const int Rrows = (ws_size >= ((size_t)232 << 20)) ? 16384
                  : (ws_size >= ((size_t)160 << 20)) ? 8192
                  : (ws_size >= ((size_t)128 << 20)) ? 4096 : 2048;

  const int SZ_QKV = 512 * 1536, SZ_P = 512 * 512, SZ_F1 = 512 * 2048, SZ_F2 = 2048 * 512;
  const int PB = (SZ_QKV + SZ_P + SZ_F1 + SZ_F2) * 2;
  short* cbH = Wb + (size_t)2 * PB;
  short* cbL = cbH + 4096 * 512;

  // ---- one-time (per launch) weight transpose + split ----
  for (int blk = 0; blk < 2; blk++) {
    short* base = Wb + (size_t)blk * PB;
    short* qH = base;          short* qL = qH + SZ_QKV;
    short* pH = qL + SZ_QKV;   short* pL = pH + SZ_P;
    short* f1H = pL + SZ_P;    short* f1L = f1H + SZ_F1;
    short* f2H = f1L + SZ_F1;  short* f2L = f2H + SZ_F2;
    wconvT_kernel<<<dim3(48, 16), dim3(32, 8), 0, stream>>>(qkvw + (size_t)blk * SZ_QKV, qH, qL, 512, 1536);
    wconvT_kernel<<<dim3(16, 16), dim3(32, 8), 0, stream>>>(pw + (size_t)blk * SZ_P, pH, pL, 512, 512);
    wconvT_kernel<<<dim3(64, 16), dim3(32, 8), 0, stream>>>(f1w + (size_t)blk * SZ_F1, f1H, f1L, 512, 2048);
    wconvT_kernel<<<dim3(16, 64), dim3(32, 8), 0, stream>>>(f2w + (size_t)blk * SZ_F2, f2H, f2L, 2048, 512);
  }
  wconv_kernel<<<2048, 256, 0, stream>>>(cb, cbH, cbL);

  const int nch = ROWS / Rrows;
  for (int blk = 0; blk < 2; blk++) {
    short* base = Wb + (size_t)blk * PB;
    short* qH = base;          short* qL = qH + SZ_QKV;
    short* pH = qL + SZ_QKV;   short* pL = pH + SZ_P;
    short* f1H = pL + SZ_P;    short* f1L = f1H + SZ_F1;
    short* f2H = f1L + SZ_F1;  short* f2L = f2H + SZ_F2;
    const float* xcur = blk ? (const float*)Abuf : x_in;
    int shift = blk ? 4 : 0;

    // LN1 + shift + window partition -> hi/lo planes (windowed order)
    ln_split_kernel<<<8192, 256, 0, stream>>>(xcur, Hbuf, Lbuf, n1g + blk * 512, n1b + blk * 512, shift, 1);

    // qkv GEMM (fp32 out) + attention (writes planes back in place)
    float* Cq = (float*)Cbuf;
    for (int ch = 0; ch < nch; ch++) {
      int r0 = ch * Rrows;
      mgemm<0><<<dim3(Rrows / 128, 12), 512, 0, stream>>>(
          Hbuf + (size_t)r0 * 512, Lbuf + (size_t)r0 * 512, qH, qL, 512,
          qkvb + blk * 1536, Cq, nullptr, nullptr, 1536,
          nullptr, 0, 0, 0);
      attn_kernel<<<dim3(Rrows / 64, 8), 256, 0, stream>>>(
          Cq, rpb + blk * 1800, Hbuf, Lbuf, r0 >> 6, shift);
    }

    // proj + window reverse + unshift + residual -> Abuf (fp32)
    mgemm<2><<<dim3(256, 4), 512, 0, stream>>>(
        Hbuf, Lbuf, pH, pL, 512, pb + blk * 512,
        Abuf, nullptr, nullptr, 512,
        blk ? (const float*)Abuf : x_in, 0, 1, shift);

    // LN2 -> planes (identity order)
    ln_split_kernel<<<8192, 256, 0, stream>>>(Abuf, Hbuf, Lbuf, n2g + blk * 512, n2b + blk * 512, 0, 0);

    // MLP; blk==1 fc2 also emits h/l planes (fused split for VQ)
    short* gh = (short*)Cbuf;
    short* gl = gh + (size_t)Rrows * 2048;
    for (int ch = 0; ch < nch; ch++) {
      int r0 = ch * Rrows;
      mgemm<1><<<dim3(Rrows / 128, 16), 512, 0, stream>>>(
          Hbuf + (size_t)r0 * 512, Lbuf + (size_t)r0 * 512, f1H, f1L, 512,
          f1b + blk * 2048, nullptr, gh, gl, 2048,
          nullptr, 0, 0, 0);
      if (blk == 0) {
        mgemm<2><<<dim3(Rrows / 128, 4), 512, 0, stream>>>(
            gh, gl, f2H, f2L, 2048, f2b_ + blk * 512,
            Abuf, nullptr, nullptr, 512,
            Abuf, r0, 0, 0);
      } else {
        mgemm<4><<<dim3(Rrows / 128, 4), 512, 0, stream>>>(
            gh, gl, f2H, f2L, 2048, f2b_ + blk * 512,
            Abuf, Hbuf, Lbuf, 512,
            Abuf, r0, 0, 0);
      }
    }
  }

  // ---- VQ: approx top-2/tile via single-pass fp16 GEMM, exact rescore ----
  float*    c2  = (float*)Cbuf;                              // 16 KB
  unsigned* pkb = (unsigned*)(Cbuf + ((size_t)64 << 10));    // 4 MiB: 32768 x 32 keys
  rowss_kernel<<<1024, 256, 0, stream>>>(cb, c2, 4096);
  vqgemm<<<4096, 512, 0, stream>>>(Hbuf, cbH, c2, pkb);
  vq_out_kernel<<<8192, 256, 0, stream>>>(pkb, Abuf, cb, outq, outidx);
}